// Round 11
// baseline (116.636 us; speedup 1.0000x reference)
//
#include <hip/hip_runtime.h>
#include <math.h>

#define TB     8       // tokens per workgroup (MFMA M=16, rows 8-15 dup)
#define CDIM   256
#define NHEADS 4
#define DHEAD  64
#define NV     8
#define LSEQ   8192
#define NB     4

typedef short  bf16x8 __attribute__((ext_vector_type(8)));
typedef float  f32x4  __attribute__((ext_vector_type(4)));
typedef unsigned short u16;

// ---- bf16 split helpers (RNE) ----
static __device__ __forceinline__ u16 f2bf(float x) {
    unsigned u = __float_as_uint(x);
    unsigned r = ((u >> 16) & 1u) + 0x7fffu;
    return (u16)((u + r) >> 16);
}
static __device__ __forceinline__ float bf2f(u16 h) {
    return __uint_as_float(((unsigned)h) << 16);
}

// =====================================================================
// Pre-pass: convert Wk, Wv (fp32) into MFMA B-fragment-ready bf16 hi/lo
// layouts in workspace (unchanged since round 3; verified).
//  wkf unit = (((h*2+kc)*16+nt)*2+s)*64 + lane ; Wk pre-scaled by 1/8.
//  wvf unit = (((h*8+kc)*4+nt)*2+s)*64 + lane.
//  (lo halves produced but unused by the main kernel.)
// =====================================================================
__global__ __launch_bounds__(256) void prep_frags(
    const float* __restrict__ Wk, const float* __restrict__ Wv,
    u16* __restrict__ wkf, u16* __restrict__ wvf)
{
    const int tid = blockIdx.x * 256 + threadIdx.x;
    union { u16 u[8]; uint4 v; } pk;
    if (tid < 16384) {                      // wkf
        int l = tid & 63; int r = tid >> 6;
        const int s  = r & 1;  r >>= 1;
        const int nt = r & 15; r >>= 4;
        const int kc = r & 1;  r >>= 1;
        const int h  = r & 3;
        const int c     = nt * 16 + (l & 15);
        const int dbase = h * DHEAD + kc * 32 + (l >> 4) * 8;
        #pragma unroll
        for (int j = 0; j < 8; ++j) {
            const float x  = Wk[(size_t)c * CDIM + dbase + j] * 0.125f;
            const u16 hi = f2bf(x);
            const u16 lo = f2bf(x - bf2f(hi));
            pk.u[j] = s ? lo : hi;
        }
        *reinterpret_cast<uint4*>(wkf + (size_t)tid * 8) = pk.v;
    } else if (tid < 32768) {               // wvf
        int t2 = tid - 16384;
        int l = t2 & 63; int r = t2 >> 6;
        const int s  = r & 1; r >>= 1;
        const int nt = r & 3; r >>= 2;
        const int kc = r & 7; r >>= 3;
        const int h  = r & 3;
        const int d     = h * DHEAD + nt * 16 + (l & 15);
        const int cbase = kc * 32 + (l >> 4) * 8;
        #pragma unroll
        for (int j = 0; j < 8; ++j) {
            const float x  = Wv[(size_t)(cbase + j) * CDIM + d];
            const u16 hi = f2bf(x);
            const u16 lo = f2bf(x - bf2f(hi));
            pk.u[j] = s ? lo : hi;
        }
        *reinterpret_cast<uint4*>(wvf + (size_t)t2 * 8) = pk.v;
    }
}

// =====================================================================
// Main fused kernel. Round-11 change: TB 16->8, 512-thread blocks,
// LDS 36 KB -> 4 blocks/CU (was 2). Round-10 pipe-sum showed near-ZERO
// phase overlap (serial sum of pipe times == measured dur): the two
// identical resident blocks convoy through the barriered phases, so
// HBM (phase B) and L2/VALU (A/C/D) never overlap. Four independent
// barrier domains de-convoy statistically. Costs accepted: weight L2
// traffic x2 (still < HBM stream), MFMA dup-rows x2 (~7% pipe).
// All r10 optimizations retained (hi-only weights+activations, folded
// 1/8 scale, 3 barriers, token-major same-wave wctx aliasing).
// =====================================================================
__global__ __launch_bounds__(512, 8) void triplane_fused(
    const float* __restrict__ q,
    const float* __restrict__ ctx,
    const u16*   __restrict__ wkf,
    const u16*   __restrict__ wvf,
    const float* __restrict__ bv,
    const float* __restrict__ gamma,
    const float* __restrict__ beta,
    float* __restrict__ out,
    float* __restrict__ probs_out)
{
    __shared__ __align__(16) float s_qk[TB * NHEADS * CDIM];  // 32768 B: fp32 qk (token-major,
                                                              // 4KB/token); lower 2KB/token reused
                                                              // as bf16 wctx by the SAME wave
    __shared__ __align__(16) u16   s_qnh[TB * CDIM];          // 4096 B qn hi (XOR-swizzled rows)
    // total 36864 B -> 4 blocks/CU (32 waves)

    const int tid  = threadIdx.x;
    const int w    = tid >> 6;    // wave 0..7
    const int lane = tid & 63;
    const int tok0 = blockIdx.x * TB;
    const f32x4 zero4 = {0.f, 0.f, 0.f, 0.f};

    const int h  = w & 3;         // head for phases A and D
    const int cg = w >> 2;        // c-half (A) / d-half (D), 0..1

    // ---------- Phase 0: LayerNorm(q) -> bf16 hi in swizzled LDS ----------
    {
        const int t = w;          // wave <-> token, 8 tokens
        const int c = lane * 4;
        const float4 qv = *reinterpret_cast<const float4*>(q + (size_t)(tok0 + t) * CDIM + c);
        float s  = qv.x + qv.y + qv.z + qv.w;
        float s2 = qv.x*qv.x + qv.y*qv.y + qv.z*qv.z + qv.w*qv.w;
        #pragma unroll
        for (int off = 32; off >= 1; off >>= 1) {
            s  += __shfl_xor(s,  off);
            s2 += __shfl_xor(s2, off);
        }
        const float mu   = s  * (1.0f / CDIM);
        const float var  = s2 * (1.0f / CDIM) - mu * mu;
        const float rstd = rsqrtf(var + 1e-5f);
        const float4 g  = *reinterpret_cast<const float4*>(gamma + c);
        const float4 be = *reinterpret_cast<const float4*>(beta + c);
        ushort4 vh;
        vh.x = f2bf((qv.x - mu) * rstd * g.x + be.x);
        vh.y = f2bf((qv.y - mu) * rstd * g.y + be.y);
        vh.z = f2bf((qv.z - mu) * rstd * g.z + be.z);
        vh.w = f2bf((qv.w - mu) * rstd * g.w + be.w);
        const int off = t * 512 + ((lane * 8) ^ (t << 4));   // byte offset, 8B aligned
        *reinterpret_cast<ushort4*>(reinterpret_cast<char*>(s_qnh) + off) = vh;
    }
    __syncthreads();

    // ---------- Phase A (MFMA): qk[t][h][c] = qn_h[t][:] . (Wk/8)_h^T[:][c] ----------
    // wave (h, cg): 128 c's (8 n-tiles). M=16 (rows 8-15 dup 0-7), K=64 (kc=0,1).
    // 1 MFMA per (nt,kc): aH * bH (qn-lo and weight-lo dropped).
    {
        const int arow = lane & 7;       // token row (dup 8-15 <- 0-7)
        const int akq  = lane >> 4;      // k quarter
        bf16x8 aH[2];
        #pragma unroll
        for (int kc = 0; kc < 2; ++kc) {
            const int intra = (h * DHEAD + kc * 32 + akq * 8) * 2;  // 16B aligned
            const int off   = arow * 512 + (intra ^ (arow << 4));
            aH[kc] = *reinterpret_cast<const bf16x8*>(reinterpret_cast<const char*>(s_qnh) + off);
        }
        #pragma unroll
        for (int nt = 0; nt < 8; ++nt) {
            const int ntg = cg * 8 + nt;          // global n-tile 0..15
            f32x4 acc = zero4;
            #pragma unroll
            for (int kc = 0; kc < 2; ++kc) {
                const u16* p = wkf + ((size_t)(h * 4096 + kc * 2048 + ntg * 128) + lane) * 8;
                const bf16x8 bH = *reinterpret_cast<const bf16x8*>(p);
                acc = __builtin_amdgcn_mfma_f32_16x16x32_bf16(aH[kc], bH, acc, 0, 0, 0);
            }
            // C layout: col = lane&15, row = (lane>>4)*4 + reg ; rows 0..7 real
            if (lane < 32) {
                const int cc = ntg * 16 + (lane & 15);
                #pragma unroll
                for (int reg = 0; reg < 4; ++reg) {
                    const int t = (lane >> 4) * 4 + reg;    // 0..7
                    s_qk[(t * NHEADS + h) * CDIM + cc] = acc[reg];   // token-major
                }
            }
        }
    }
    __syncthreads();

    // ---------- Phase B + softmax (all in registers) ----------
    // scores[t][h][n] = sum_c ctx[t][n][c]*qk[t][h][c]   (1/8 folded into Wk)
    // lane = (n = lane>>3, cs = lane&7); reduce over cs (3 shfl levels),
    // then softmax over n-groups (shfl offs 8/16/32). p0..p3 = probs(t,n,h0..3).
    float p0, p1, p2, p3;
    {
        const int t  = w;
        const int cs = lane & 7;
        const float* cb = ctx + ((size_t)(tok0 + t) * NV + (lane >> 3)) * CDIM + cs * 4;
        p0 = 0.f; p1 = 0.f; p2 = 0.f; p3 = 0.f;
        #pragma unroll
        for (int i = 0; i < 8; ++i) {
            const int c = i * 32 + cs * 4;
            const float4 cv = *reinterpret_cast<const float4*>(cb + i * 32);
            const float4 k0 = *reinterpret_cast<const float4*>(&s_qk[(t*NHEADS+0)*CDIM + c]);
            const float4 k1 = *reinterpret_cast<const float4*>(&s_qk[(t*NHEADS+1)*CDIM + c]);
            const float4 k2 = *reinterpret_cast<const float4*>(&s_qk[(t*NHEADS+2)*CDIM + c]);
            const float4 k3 = *reinterpret_cast<const float4*>(&s_qk[(t*NHEADS+3)*CDIM + c]);
            p0 += cv.x*k0.x + cv.y*k0.y + cv.z*k0.z + cv.w*k0.w;
            p1 += cv.x*k1.x + cv.y*k1.y + cv.z*k1.z + cv.w*k1.w;
            p2 += cv.x*k2.x + cv.y*k2.y + cv.z*k2.z + cv.w*k2.w;
            p3 += cv.x*k3.x + cv.y*k3.y + cv.z*k3.z + cv.w*k3.w;
        }
        #pragma unroll
        for (int off = 4; off >= 1; off >>= 1) {
            p0 += __shfl_xor(p0, off);
            p1 += __shfl_xor(p1, off);
            p2 += __shfl_xor(p2, off);
            p3 += __shfl_xor(p3, off);
        }
        // softmax over n (lane bits 3..5)
        float m0 = p0, m1 = p1, m2 = p2, m3 = p3;
        #pragma unroll
        for (int off = 8; off <= 32; off <<= 1) {
            m0 = fmaxf(m0, __shfl_xor(m0, off));
            m1 = fmaxf(m1, __shfl_xor(m1, off));
            m2 = fmaxf(m2, __shfl_xor(m2, off));
            m3 = fmaxf(m3, __shfl_xor(m3, off));
        }
        p0 = __expf(p0 - m0); p1 = __expf(p1 - m1);
        p2 = __expf(p2 - m2); p3 = __expf(p3 - m3);
        float s0 = p0, s1 = p1, s2 = p2, s3 = p3;
        #pragma unroll
        for (int off = 8; off <= 32; off <<= 1) {
            s0 += __shfl_xor(s0, off);
            s1 += __shfl_xor(s1, off);
            s2 += __shfl_xor(s2, off);
            s3 += __shfl_xor(s3, off);
        }
        p0 /= s0; p1 /= s1; p2 /= s2; p3 /= s3;
        // probs_out store: lanes cs==0 write their n for all 4 heads
        if (cs == 0) {
            const int tok = tok0 + t;
            const int b = tok >> 13;
            const int l = tok & (LSEQ - 1);
            const int n = lane >> 3;
            float* pb = probs_out + (((size_t)b * NHEADS) * LSEQ + l) * NV + n;
            pb[0 * LSEQ * NV] = p0;
            pb[1 * LSEQ * NV] = p1;
            pb[2 * LSEQ * NV] = p2;
            pb[3 * LSEQ * NV] = p3;
        }
    }
    // NO barrier: phase C only overwrites THIS wave's token slot in s_qk,
    // which only THIS wave read in phase B (token-major layout).

    // ---------- Phase C: wctx[t][h][c] -> bf16 HI into token t's own qk slot ----------
    // write addr: t*4096 + h*512 + (lane*8 ^ (t<<4))  [bytes]
    {
        const int t = w;
        const float* cbase = ctx + ((size_t)(tok0 + t) * NV) * CDIM + lane * 4;
        float4 a0, a1, a2, a3;
        a0.x=a0.y=a0.z=a0.w=0.f; a1=a0; a2=a0; a3=a0;
        #pragma unroll
        for (int n = 0; n < NV; ++n) {
            const float prx = __shfl(p0, n * 8);
            const float pry = __shfl(p1, n * 8);
            const float prz = __shfl(p2, n * 8);
            const float prw = __shfl(p3, n * 8);
            const float4 cv = *reinterpret_cast<const float4*>(cbase + (size_t)n * CDIM);
            a0.x += prx*cv.x; a0.y += prx*cv.y; a0.z += prx*cv.z; a0.w += prx*cv.w;
            a1.x += pry*cv.x; a1.y += pry*cv.y; a1.z += pry*cv.z; a1.w += pry*cv.w;
            a2.x += prz*cv.x; a2.y += prz*cv.y; a2.z += prz*cv.z; a2.w += prz*cv.w;
            a3.x += prw*cv.x; a3.y += prw*cv.y; a3.z += prw*cv.z; a3.w += prw*cv.w;
        }
        char* base = reinterpret_cast<char*>(s_qk) + t * 4096;
        const int xo = (lane * 8) ^ (t << 4);
        #pragma unroll
        for (int hh = 0; hh < 4; ++hh) {
            const float4 v = (hh == 0) ? a0 : (hh == 1) ? a1 : (hh == 2) ? a2 : a3;
            ushort4 vh;
            vh.x = f2bf(v.x); vh.y = f2bf(v.y); vh.z = f2bf(v.z); vh.w = f2bf(v.w);
            *reinterpret_cast<ushort4*>(base + hh * 512 + xo) = vh;
        }
    }
    __syncthreads();   // phase D reads all tokens' wctx (cross-wave)

    // ---------- Phase D (MFMA): out[t][h*64+d] = wctx_h[t][:] . Wv_h[:][d] + bv ----------
    // wave (h, cg): two 16-d n-tiles. K=256 (8 kc); aH read once per kc.
    // wctx read token-major: arow*4096 + h*512 + ((kc*64+akq*16) ^ (arow<<4))
    {
        const int arow = lane & 7;       // token row (dup 8-15 <- 0-7)
        const int akq  = lane >> 4;
        const int nt0  = cg * 2, nt1 = cg * 2 + 1;
        const char* wch = reinterpret_cast<const char*>(s_qk);
        const u16* wvbase = wvf + ((size_t)(h * 4096) + lane) * 8;
        f32x4 acc0 = zero4, acc1 = zero4;
        #pragma unroll
        for (int kc = 0; kc < 8; ++kc) {
            const int intra = kc * 64 + akq * 16;
            const int off   = arow * 4096 + h * 512 + (intra ^ (arow << 4));
            const bf16x8 aH = *reinterpret_cast<const bf16x8*>(wch + off);
            const u16* pp0 = wvbase + (size_t)(kc * 512 + nt0 * 128) * 8;
            const u16* pp1 = wvbase + (size_t)(kc * 512 + nt1 * 128) * 8;
            const bf16x8 bH0 = *reinterpret_cast<const bf16x8*>(pp0);
            const bf16x8 bH1 = *reinterpret_cast<const bf16x8*>(pp1);
            acc0 = __builtin_amdgcn_mfma_f32_16x16x32_bf16(aH, bH0, acc0, 0, 0, 0);
            acc1 = __builtin_amdgcn_mfma_f32_16x16x32_bf16(aH, bH1, acc1, 0, 0, 0);
        }
        if (lane < 32) {
            const int tt = (lane >> 4) * 4;      // row base 0 or 4
            {
                const int d = h * DHEAD + nt0 * 16 + (lane & 15);
                const float bvv = bv[d];
                #pragma unroll
                for (int reg = 0; reg < 4; ++reg)
                    out[(size_t)(tok0 + tt + reg) * CDIM + d] = acc0[reg] + bvv;
            }
            {
                const int d = h * DHEAD + nt1 * 16 + (lane & 15);
                const float bvv = bv[d];
                #pragma unroll
                for (int reg = 0; reg < 4; ++reg)
                    out[(size_t)(tok0 + tt + reg) * CDIM + d] = acc1[reg] + bvv;
            }
        }
    }
}

// =====================================================================
// Fallback (round-1 vector kernel) if workspace is too small.
// =====================================================================
#define TBF 8
__global__ __launch_bounds__(512, 6) void triplane_fused_v1(
    const float* __restrict__ q, const float* __restrict__ ctx,
    const float* __restrict__ Wk, const float* __restrict__ Wv,
    const float* __restrict__ bv, const float* __restrict__ gamma,
    const float* __restrict__ beta, float* __restrict__ out,
    float* __restrict__ probs_out)
{
    __shared__ float s_qn[TBF * CDIM];
    __shared__ float s_qk[TBF * NHEADS * CDIM];
    __shared__ float s_sc[TBF * NV * NHEADS];
    const int tid  = threadIdx.x;
    const int w    = tid >> 6;
    const int lane = tid & 63;
    const int tok0 = blockIdx.x * TBF;
    {
        const int t = w; const int c = lane * 4;
        const float4 qv = *reinterpret_cast<const float4*>(q + (size_t)(tok0 + t) * CDIM + c);
        float s  = qv.x + qv.y + qv.z + qv.w;
        float s2 = qv.x*qv.x + qv.y*qv.y + qv.z*qv.z + qv.w*qv.w;
        #pragma unroll
        for (int off = 32; off >= 1; off >>= 1) { s += __shfl_xor(s, off); s2 += __shfl_xor(s2, off); }
        const float mu = s * (1.0f/CDIM);
        const float var = s2 * (1.0f/CDIM) - mu*mu;
        const float rstd = rsqrtf(var + 1e-5f);
        const float4 g  = *reinterpret_cast<const float4*>(gamma + c);
        const float4 be = *reinterpret_cast<const float4*>(beta + c);
        float4 qn;
        qn.x=(qv.x-mu)*rstd*g.x+be.x; qn.y=(qv.y-mu)*rstd*g.y+be.y;
        qn.z=(qv.z-mu)*rstd*g.z+be.z; qn.w=(qv.w-mu)*rstd*g.w+be.w;
        *reinterpret_cast<float4*>(&s_qn[t*CDIM + c]) = qn;
    }
    __syncthreads();
    {
        const int h = w & 3; const int cg = w >> 2;
        const int c0 = cg*128 + lane; const int c1 = c0 + 64;
        const float* wk0 = Wk + (size_t)c0*CDIM + h*DHEAD;
        const float* wk1 = Wk + (size_t)c1*CDIM + h*DHEAD;
        float acc0[TBF], acc1[TBF];
        #pragma unroll
        for (int t = 0; t < TBF; ++t) { acc0[t]=0.f; acc1[t]=0.f; }
        for (int d4 = 0; d4 < DHEAD/4; ++d4) {
            const float4 wa = *reinterpret_cast<const float4*>(wk0 + d4*4);
            const float4 wb = *reinterpret_cast<const float4*>(wk1 + d4*4);
            #pragma unroll
            for (int t = 0; t < TBF; ++t) {
                const float4 qv = *reinterpret_cast<const float4*>(&s_qn[t*CDIM + h*DHEAD + d4*4]);
                acc0[t] += qv.x*wa.x + qv.y*wa.y + qv.z*wa.z + qv.w*wa.w;
                acc1[t] += qv.x*wb.x + qv.y*wb.y + qv.z*wb.z + qv.w*wb.w;
            }
        }
        #pragma unroll
        for (int t = 0; t < TBF; ++t) {
            s_qk[(t*NHEADS+h)*CDIM + c0] = acc0[t];
            s_qk[(t*NHEADS+h)*CDIM + c1] = acc1[t];
        }
    }
    __syncthreads();
    {
        const int t = w; const int n = lane >> 3; const int cs = lane & 7;
        const float* cb = ctx + ((size_t)(tok0 + t)*NV + n)*CDIM;
        float p0=0,p1=0,p2=0,p3=0;
        #pragma unroll
        for (int i = 0; i < 8; ++i) {
            const int c = i*32 + cs*4;
            const float4 cv = *reinterpret_cast<const float4*>(cb + c);
            const float4 k0 = *reinterpret_cast<const float4*>(&s_qk[(t*NHEADS+0)*CDIM + c]);
            const float4 k1 = *reinterpret_cast<const float4*>(&s_qk[(t*NHEADS+1)*CDIM + c]);
            const float4 k2 = *reinterpret_cast<const float4*>(&s_qk[(t*NHEADS+2)*CDIM + c]);
            const float4 k3 = *reinterpret_cast<const float4*>(&s_qk[(t*NHEADS+3)*CDIM + c]);
            p0 += cv.x*k0.x+cv.y*k0.y+cv.z*k0.z+cv.w*k0.w;
            p1 += cv.x*k1.x+cv.y*k1.y+cv.z*k1.z+cv.w*k1.w;
            p2 += cv.x*k2.x+cv.y*k2.y+cv.z*k2.z+cv.w*k2.w;
            p3 += cv.x*k3.x+cv.y*k3.y+cv.z*k3.z+cv.w*k3.w;
        }
        #pragma unroll
        for (int off = 4; off >= 1; off >>= 1) {
            p0 += __shfl_xor(p0, off); p1 += __shfl_xor(p1, off);
            p2 += __shfl_xor(p2, off); p3 += __shfl_xor(p3, off);
        }
        if (cs == 0) {
            s_sc[(t*NV+n)*NHEADS+0] = p0*0.125f; s_sc[(t*NV+n)*NHEADS+1] = p1*0.125f;
            s_sc[(t*NV+n)*NHEADS+2] = p2*0.125f; s_sc[(t*NV+n)*NHEADS+3] = p3*0.125f;
        }
    }
    __syncthreads();
    float* s_out = s_qn;
    {
        float4 z; z.x=z.y=z.z=z.w=0.f;
        reinterpret_cast<float4*>(s_out)[tid] = z;
        if (tid < TBF*NHEADS) {
            const int t = tid >> 2; const int h = tid & 3;
            float sc[NV]; float m = -1e30f;
            #pragma unroll
            for (int n = 0; n < NV; ++n) { sc[n] = s_sc[(t*NV+n)*NHEADS+h]; m = fmaxf(m, sc[n]); }
            float sum = 0.f;
            #pragma unroll
            for (int n = 0; n < NV; ++n) { sc[n] = __expf(sc[n]-m); sum += sc[n]; }
            const float inv = 1.f/sum;
            const int tok = tok0 + t; const int b = tok >> 13; const int l = tok & (LSEQ-1);
            float* pdst = probs_out + (((size_t)b*NHEADS + h)*LSEQ + l)*NV;
            #pragma unroll
            for (int n = 0; n < NV; ++n) { const float p = sc[n]*inv; s_sc[(t*NV+n)*NHEADS+h] = p; pdst[n] = p; }
        }
    }
    __syncthreads();
    {
        const int t = w;
        const float* cbase = ctx + ((size_t)(tok0 + t)*NV)*CDIM;
        float4 a0,a1,a2,a3; a0.x=a0.y=a0.z=a0.w=0.f; a1=a0; a2=a0; a3=a0;
        for (int n = 0; n < NV; ++n) {
            const float4 pr = *reinterpret_cast<const float4*>(&s_sc[(t*NV+n)*NHEADS]);
            const float4 cv = *reinterpret_cast<const float4*>(cbase + (size_t)n*CDIM + lane*4);
            a0.x+=pr.x*cv.x; a0.y+=pr.x*cv.y; a0.z+=pr.x*cv.z; a0.w+=pr.x*cv.w;
            a1.x+=pr.y*cv.x; a1.y+=pr.y*cv.y; a1.z+=pr.y*cv.z; a1.w+=pr.y*cv.w;
            a2.x+=pr.z*cv.x; a2.y+=pr.z*cv.y; a2.z+=pr.z*cv.z; a2.w+=pr.z*cv.w;
            a3.x+=pr.w*cv.x; a3.y+=pr.w*cv.y; a3.z+=pr.w*cv.z; a3.w+=pr.w*cv.w;
        }
        *reinterpret_cast<float4*>(&s_qk[(t*NHEADS+0)*CDIM + lane*4]) = a0;
        *reinterpret_cast<float4*>(&s_qk[(t*NHEADS+1)*CDIM + lane*4]) = a1;
        *reinterpret_cast<float4*>(&s_qk[(t*NHEADS+2)*CDIM + lane*4]) = a2;
        *reinterpret_cast<float4*>(&s_qk[(t*NHEADS+3)*CDIM + lane*4]) = a3;
    }
    __syncthreads();
    {
        const int h = w & 3; const int cg = w >> 2;
        float acc[TBF];
        #pragma unroll
        for (int t = 0; t < TBF; ++t) acc[t] = 0.f;
        const float* wvbase = Wv + h*DHEAD + lane;
        for (int c4 = 0; c4 < 32; ++c4) {
            const int c = cg*128 + c4*4;
            const float wv0 = wvbase[(size_t)(c+0)*CDIM];
            const float wv1 = wvbase[(size_t)(c+1)*CDIM];
            const float wv2 = wvbase[(size_t)(c+2)*CDIM];
            const float wv3 = wvbase[(size_t)(c+3)*CDIM];
            #pragma unroll
            for (int t = 0; t < TBF; ++t) {
                const float4 wc = *reinterpret_cast<const float4*>(&s_qk[(t*NHEADS+h)*CDIM + c]);
                acc[t] += wc.x*wv0 + wc.y*wv1 + wc.z*wv2 + wc.w*wv3;
            }
        }
        #pragma unroll
        for (int t = 0; t < TBF; ++t) atomicAdd(&s_out[t*CDIM + h*DHEAD + lane], acc[t]);
    }
    __syncthreads();
    {
        const int t = w; const int c = lane * 4;
        float4 o = *reinterpret_cast<const float4*>(&s_out[t*CDIM + c]);
        const float4 bvv = *reinterpret_cast<const float4*>(bv + c);
        o.x += bvv.x; o.y += bvv.y; o.z += bvv.z; o.w += bvv.w;
        *reinterpret_cast<float4*>(out + (size_t)(tok0 + t)*CDIM + c) = o;
    }
}

extern "C" void kernel_launch(void* const* d_in, const int* in_sizes, int n_in,
                              void* d_out, int out_size, void* d_ws, size_t ws_size,
                              hipStream_t stream) {
    const float* q     = (const float*)d_in[0];
    const float* ctx   = (const float*)d_in[1];
    const float* Wk    = (const float*)d_in[2];
    // d_in[3] = bk: per-(t,h) constant across the Nv scores -> cancels in softmax; unused.
    const float* Wv    = (const float*)d_in[4];
    const float* bv    = (const float*)d_in[5];
    const float* gamma = (const float*)d_in[6];
    const float* beta  = (const float*)d_in[7];

    float* out   = (float*)d_out;
    float* probs = out + (size_t)NB * LSEQ * CDIM;

    const int n_tok = NB * LSEQ;               // 32768
    const size_t ws_need = (size_t)2 * 131072 * sizeof(u16);   // 512 KB

    if (d_ws != nullptr && ws_size >= ws_need) {
        u16* wkf = (u16*)d_ws;
        u16* wvf = wkf + 131072;
        hipLaunchKernelGGL(prep_frags, dim3(128), dim3(256), 0, stream, Wk, Wv, wkf, wvf);
        hipLaunchKernelGGL(triplane_fused, dim3(n_tok / TB), dim3(512), 0, stream,
                           q, ctx, wkf, wvf, bv, gamma, beta, out, probs);
    } else {
        hipLaunchKernelGGL(triplane_fused_v1, dim3(n_tok / TBF), dim3(512), 0, stream,
                           q, ctx, Wk, Wv, bv, gamma, beta, out, probs);
    }
}

// Round 12
// 97.459 us; speedup vs baseline: 1.1968x; 1.1968x over previous
//
#include <hip/hip_runtime.h>
#include <math.h>

#define TB     16      // tokens per workgroup (= MFMA M, all real rows)
#define CDIM   256
#define NHEADS 4
#define DHEAD  64
#define NV     8
#define LSEQ   8192
#define NB     4

typedef short  bf16x8 __attribute__((ext_vector_type(8)));
typedef float  f32x4  __attribute__((ext_vector_type(4)));
typedef unsigned short u16;

// ---- bf16 split helpers (RNE) ----
static __device__ __forceinline__ u16 f2bf(float x) {
    unsigned u = __float_as_uint(x);
    unsigned r = ((u >> 16) & 1u) + 0x7fffu;
    return (u16)((u + r) >> 16);
}
static __device__ __forceinline__ float bf2f(u16 h) {
    return __uint_as_float(((unsigned)h) << 16);
}

// =====================================================================
// Pre-pass: convert Wk, Wv (fp32) into MFMA B-fragment-ready bf16 hi/lo
// layouts in workspace (unchanged since round 3; verified).
//  wkf unit = (((h*2+kc)*16+nt)*2+s)*64 + lane ; Wk pre-scaled by 1/8.
//  wvf unit = (((h*8+kc)*4+nt)*2+s)*64 + lane.
//  (lo halves produced but unused by the main kernel.)
// =====================================================================
__global__ __launch_bounds__(256) void prep_frags(
    const float* __restrict__ Wk, const float* __restrict__ Wv,
    u16* __restrict__ wkf, u16* __restrict__ wvf)
{
    const int tid = blockIdx.x * 256 + threadIdx.x;
    union { u16 u[8]; uint4 v; } pk;
    if (tid < 16384) {                      // wkf
        int l = tid & 63; int r = tid >> 6;
        const int s  = r & 1;  r >>= 1;
        const int nt = r & 15; r >>= 4;
        const int kc = r & 1;  r >>= 1;
        const int h  = r & 3;
        const int c     = nt * 16 + (l & 15);
        const int dbase = h * DHEAD + kc * 32 + (l >> 4) * 8;
        #pragma unroll
        for (int j = 0; j < 8; ++j) {
            const float x  = Wk[(size_t)c * CDIM + dbase + j] * 0.125f;
            const u16 hi = f2bf(x);
            const u16 lo = f2bf(x - bf2f(hi));
            pk.u[j] = s ? lo : hi;
        }
        *reinterpret_cast<uint4*>(wkf + (size_t)tid * 8) = pk.v;
    } else if (tid < 32768) {               // wvf
        int t2 = tid - 16384;
        int l = t2 & 63; int r = t2 >> 6;
        const int s  = r & 1; r >>= 1;
        const int nt = r & 3; r >>= 2;
        const int kc = r & 7; r >>= 3;
        const int h  = r & 3;
        const int d     = h * DHEAD + nt * 16 + (l & 15);
        const int cbase = kc * 32 + (l >> 4) * 8;
        #pragma unroll
        for (int j = 0; j < 8; ++j) {
            const float x  = Wv[(size_t)(cbase + j) * CDIM + d];
            const u16 hi = f2bf(x);
            const u16 lo = f2bf(x - bf2f(hi));
            pk.u[j] = s ? lo : hi;
        }
        *reinterpret_cast<uint4*>(wvf + (size_t)t2 * 8) = pk.v;
    }
}

// =====================================================================
// Main fused kernel. Round-12 = round-10 (verified 101.5 us; round-11's
// TB=8 de-convoy REGRESSED via doubled weight-L2 traffic -> reverted)
// plus one micro-fix: probs_out stores deferred from phase B to after
// phase D, removing 16 scattered global stores per wave from the C->D
// barrier's vmcnt(0) drain.
// Structure: TB=16, 1024 thr, LDS 72KB -> 2 blocks/CU (32 waves);
// hi-only weights+activations; 1/8 scale folded into wkf; 3 barriers;
// token-major qk with same-wave wctx aliasing (no B->C barrier).
// =====================================================================
__global__ __launch_bounds__(1024, 8) void triplane_fused(
    const float* __restrict__ q,
    const float* __restrict__ ctx,
    const u16*   __restrict__ wkf,
    const u16*   __restrict__ wvf,
    const float* __restrict__ bv,
    const float* __restrict__ gamma,
    const float* __restrict__ beta,
    float* __restrict__ out,
    float* __restrict__ probs_out)
{
    __shared__ __align__(16) float s_qk[TB * NHEADS * CDIM];  // 65536 B: fp32 qk (token-major,
                                                              // 4KB/token); lower 2KB/token reused
                                                              // as bf16 wctx by the SAME wave
    __shared__ __align__(16) u16   s_qnh[TB * CDIM];          // 8192 B qn hi (XOR-swizzled rows)
    // total 73728 B -> 2 blocks/CU (32 waves)

    const int tid  = threadIdx.x;
    const int w    = tid >> 6;    // wave 0..15
    const int lane = tid & 63;
    const int tok0 = blockIdx.x * TB;
    const f32x4 zero4 = {0.f, 0.f, 0.f, 0.f};

    const int h  = w & 3;         // head for phases A and D
    const int cq = w >> 2;        // c-quarter (A) / d-quarter (D), 0..3

    // ---------- Phase 0: LayerNorm(q) -> bf16 hi in swizzled LDS ----------
    {
        const int t = w;          // wave <-> token, 16 tokens
        const int c = lane * 4;
        const float4 qv = *reinterpret_cast<const float4*>(q + (size_t)(tok0 + t) * CDIM + c);
        float s  = qv.x + qv.y + qv.z + qv.w;
        float s2 = qv.x*qv.x + qv.y*qv.y + qv.z*qv.z + qv.w*qv.w;
        #pragma unroll
        for (int off = 32; off >= 1; off >>= 1) {
            s  += __shfl_xor(s,  off);
            s2 += __shfl_xor(s2, off);
        }
        const float mu   = s  * (1.0f / CDIM);
        const float var  = s2 * (1.0f / CDIM) - mu * mu;
        const float rstd = rsqrtf(var + 1e-5f);
        const float4 g  = *reinterpret_cast<const float4*>(gamma + c);
        const float4 be = *reinterpret_cast<const float4*>(beta + c);
        ushort4 vh;
        vh.x = f2bf((qv.x - mu) * rstd * g.x + be.x);
        vh.y = f2bf((qv.y - mu) * rstd * g.y + be.y);
        vh.z = f2bf((qv.z - mu) * rstd * g.z + be.z);
        vh.w = f2bf((qv.w - mu) * rstd * g.w + be.w);
        const int off = t * 512 + ((lane * 8) ^ (t << 4));   // byte offset, 8B aligned
        *reinterpret_cast<ushort4*>(reinterpret_cast<char*>(s_qnh) + off) = vh;
    }
    __syncthreads();

    // ---------- Phase A (MFMA): qk[t][h][c] = qn_h[t][:] . (Wk/8)_h^T[:][c] ----------
    // wave (h, cq): 64 c's (4 n-tiles). M=16 real tokens, K=64 (kc=0,1).
    // 1 MFMA per (nt,kc): aH * bH (qn-lo and weight-lo dropped).
    {
        const int arow = lane & 15;      // token row (real)
        const int akq  = lane >> 4;      // k quarter
        bf16x8 aH[2];
        #pragma unroll
        for (int kc = 0; kc < 2; ++kc) {
            const int intra = (h * DHEAD + kc * 32 + akq * 8) * 2;  // 16B aligned
            const int off   = arow * 512 + (intra ^ (arow << 4));
            aH[kc] = *reinterpret_cast<const bf16x8*>(reinterpret_cast<const char*>(s_qnh) + off);
        }
        #pragma unroll
        for (int nt = 0; nt < 4; ++nt) {
            const int ntg = cq * 4 + nt;          // global n-tile 0..15
            f32x4 acc = zero4;
            #pragma unroll
            for (int kc = 0; kc < 2; ++kc) {
                const u16* p = wkf + ((size_t)(h * 4096 + kc * 2048 + ntg * 128) + lane) * 8;
                const bf16x8 bH = *reinterpret_cast<const bf16x8*>(p);
                acc = __builtin_amdgcn_mfma_f32_16x16x32_bf16(aH[kc], bH, acc, 0, 0, 0);
            }
            // C layout: col = lane&15, row = (lane>>4)*4 + reg ; all 16 rows real
            const int cc = ntg * 16 + (lane & 15);
            #pragma unroll
            for (int reg = 0; reg < 4; ++reg) {
                const int t = (lane >> 4) * 4 + reg;
                s_qk[(t * NHEADS + h) * CDIM + cc] = acc[reg];   // token-major: t*1024 + h*256 + c
            }
        }
    }
    __syncthreads();

    // ---------- Phase B + softmax (all in registers) ----------
    // scores[t][h][n] = sum_c ctx[t][n][c]*qk[t][h][c]   (1/8 folded into Wk)
    // lane = (n = lane>>3, cs = lane&7); reduce over cs (3 shfl levels),
    // then softmax over n-groups (shfl offs 8/16/32). p0..p3 = probs(t,n,h0..3).
    float p0, p1, p2, p3;
    {
        const int t  = w;
        const int cs = lane & 7;
        const float* cb = ctx + ((size_t)(tok0 + t) * NV + (lane >> 3)) * CDIM + cs * 4;
        p0 = 0.f; p1 = 0.f; p2 = 0.f; p3 = 0.f;
        #pragma unroll
        for (int i = 0; i < 8; ++i) {
            const int c = i * 32 + cs * 4;
            const float4 cv = *reinterpret_cast<const float4*>(cb + i * 32);
            const float4 k0 = *reinterpret_cast<const float4*>(&s_qk[(t*NHEADS+0)*CDIM + c]);
            const float4 k1 = *reinterpret_cast<const float4*>(&s_qk[(t*NHEADS+1)*CDIM + c]);
            const float4 k2 = *reinterpret_cast<const float4*>(&s_qk[(t*NHEADS+2)*CDIM + c]);
            const float4 k3 = *reinterpret_cast<const float4*>(&s_qk[(t*NHEADS+3)*CDIM + c]);
            p0 += cv.x*k0.x + cv.y*k0.y + cv.z*k0.z + cv.w*k0.w;
            p1 += cv.x*k1.x + cv.y*k1.y + cv.z*k1.z + cv.w*k1.w;
            p2 += cv.x*k2.x + cv.y*k2.y + cv.z*k2.z + cv.w*k2.w;
            p3 += cv.x*k3.x + cv.y*k3.y + cv.z*k3.z + cv.w*k3.w;
        }
        #pragma unroll
        for (int off = 4; off >= 1; off >>= 1) {
            p0 += __shfl_xor(p0, off);
            p1 += __shfl_xor(p1, off);
            p2 += __shfl_xor(p2, off);
            p3 += __shfl_xor(p3, off);
        }
        // softmax over n (lane bits 3..5)
        float m0 = p0, m1 = p1, m2 = p2, m3 = p3;
        #pragma unroll
        for (int off = 8; off <= 32; off <<= 1) {
            m0 = fmaxf(m0, __shfl_xor(m0, off));
            m1 = fmaxf(m1, __shfl_xor(m1, off));
            m2 = fmaxf(m2, __shfl_xor(m2, off));
            m3 = fmaxf(m3, __shfl_xor(m3, off));
        }
        p0 = __expf(p0 - m0); p1 = __expf(p1 - m1);
        p2 = __expf(p2 - m2); p3 = __expf(p3 - m3);
        float s0 = p0, s1 = p1, s2 = p2, s3 = p3;
        #pragma unroll
        for (int off = 8; off <= 32; off <<= 1) {
            s0 += __shfl_xor(s0, off);
            s1 += __shfl_xor(s1, off);
            s2 += __shfl_xor(s2, off);
            s3 += __shfl_xor(s3, off);
        }
        p0 /= s0; p1 /= s1; p2 /= s2; p3 /= s3;
        // probs_out store DEFERRED to after phase D (keeps the C->D
        // barrier's vmcnt(0) drain free of these 16 scattered stores).
    }
    // NO barrier: phase C below only overwrites THIS wave's token slot in
    // s_qk, which only THIS wave read in phase B (token-major layout).

    // ---------- Phase C: wctx[t][h][c] -> bf16 HI into token t's own qk slot ----------
    // write addr: t*4096 + h*512 + (lane*8 ^ ((t&7)<<4))  [bytes]
    {
        const int t = w;
        const float* cbase = ctx + ((size_t)(tok0 + t) * NV) * CDIM + lane * 4;
        float4 a0, a1, a2, a3;
        a0.x=a0.y=a0.z=a0.w=0.f; a1=a0; a2=a0; a3=a0;
        #pragma unroll
        for (int n = 0; n < NV; ++n) {
            const float prx = __shfl(p0, n * 8);
            const float pry = __shfl(p1, n * 8);
            const float prz = __shfl(p2, n * 8);
            const float prw = __shfl(p3, n * 8);
            const float4 cv = *reinterpret_cast<const float4*>(cbase + (size_t)n * CDIM);
            a0.x += prx*cv.x; a0.y += prx*cv.y; a0.z += prx*cv.z; a0.w += prx*cv.w;
            a1.x += pry*cv.x; a1.y += pry*cv.y; a1.z += pry*cv.z; a1.w += pry*cv.w;
            a2.x += prz*cv.x; a2.y += prz*cv.y; a2.z += prz*cv.z; a2.w += prz*cv.w;
            a3.x += prw*cv.x; a3.y += prw*cv.y; a3.z += prw*cv.z; a3.w += prw*cv.w;
        }
        char* base = reinterpret_cast<char*>(s_qk) + t * 4096;
        const int xo = (lane * 8) ^ ((t & 7) << 4);
        #pragma unroll
        for (int hh = 0; hh < 4; ++hh) {
            const float4 v = (hh == 0) ? a0 : (hh == 1) ? a1 : (hh == 2) ? a2 : a3;
            ushort4 vh;
            vh.x = f2bf(v.x); vh.y = f2bf(v.y); vh.z = f2bf(v.z); vh.w = f2bf(v.w);
            *reinterpret_cast<ushort4*>(base + hh * 512 + xo) = vh;
        }
    }
    __syncthreads();   // phase D reads all tokens' wctx (cross-wave)

    // ---------- Phase D (MFMA): out[t][h*64+d] = wctx_h[t][:] . Wv_h[:][d] + bv ----------
    // wave (h, dq): one 16-d n-tile. K=256 (8 kc chunks); 1 MFMA per kc.
    // wctx read token-major: arow*4096 + h*512 + ((kc*64+akq*16) ^ ((arow&7)<<4))
    {
        const int arow = lane & 15;      // token row (real)
        const int akq  = lane >> 4;
        const int nt   = cq;             // d-quarter = n-tile
        const char* wch = reinterpret_cast<const char*>(s_qk);
        const u16* wvbase = wvf + ((size_t)(h * 4096) + lane) * 8;
        f32x4 acc = zero4;
        #pragma unroll
        for (int kc = 0; kc < 8; ++kc) {
            const int intra = kc * 64 + akq * 16;
            const int off   = arow * 4096 + h * 512 + (intra ^ ((arow & 7) << 4));
            const bf16x8 aH = *reinterpret_cast<const bf16x8*>(wch + off);
            const u16* pp = wvbase + (size_t)(kc * 512 + nt * 128) * 8;
            const bf16x8 bH = *reinterpret_cast<const bf16x8*>(pp);
            acc = __builtin_amdgcn_mfma_f32_16x16x32_bf16(aH, bH, acc, 0, 0, 0);
        }
        const int d = h * DHEAD + nt * 16 + (lane & 15);
        const float bvv = bv[d];
        #pragma unroll
        for (int reg = 0; reg < 4; ++reg) {
            const int t = (lane >> 4) * 4 + reg;
            out[(size_t)(tok0 + t) * CDIM + d] = acc[reg] + bvv;
        }
    }

    // ---------- Deferred probs_out store (from phase B registers) ----------
    {
        const int cs = lane & 7;
        if (cs == 0) {
            const int t = w;
            const int tok = tok0 + t;
            const int b = tok >> 13;
            const int l = tok & (LSEQ - 1);
            const int n = lane >> 3;
            float* pb = probs_out + (((size_t)b * NHEADS) * LSEQ + l) * NV + n;
            pb[0 * LSEQ * NV] = p0;
            pb[1 * LSEQ * NV] = p1;
            pb[2 * LSEQ * NV] = p2;
            pb[3 * LSEQ * NV] = p3;
        }
    }
}

// =====================================================================
// Fallback (round-1 vector kernel) if workspace is too small.
// =====================================================================
#define TBF 8
__global__ __launch_bounds__(512, 6) void triplane_fused_v1(
    const float* __restrict__ q, const float* __restrict__ ctx,
    const float* __restrict__ Wk, const float* __restrict__ Wv,
    const float* __restrict__ bv, const float* __restrict__ gamma,
    const float* __restrict__ beta, float* __restrict__ out,
    float* __restrict__ probs_out)
{
    __shared__ float s_qn[TBF * CDIM];
    __shared__ float s_qk[TBF * NHEADS * CDIM];
    __shared__ float s_sc[TBF * NV * NHEADS];
    const int tid  = threadIdx.x;
    const int w    = tid >> 6;
    const int lane = tid & 63;
    const int tok0 = blockIdx.x * TBF;
    {
        const int t = w; const int c = lane * 4;
        const float4 qv = *reinterpret_cast<const float4*>(q + (size_t)(tok0 + t) * CDIM + c);
        float s  = qv.x + qv.y + qv.z + qv.w;
        float s2 = qv.x*qv.x + qv.y*qv.y + qv.z*qv.z + qv.w*qv.w;
        #pragma unroll
        for (int off = 32; off >= 1; off >>= 1) { s += __shfl_xor(s, off); s2 += __shfl_xor(s2, off); }
        const float mu = s * (1.0f/CDIM);
        const float var = s2 * (1.0f/CDIM) - mu*mu;
        const float rstd = rsqrtf(var + 1e-5f);
        const float4 g  = *reinterpret_cast<const float4*>(gamma + c);
        const float4 be = *reinterpret_cast<const float4*>(beta + c);
        float4 qn;
        qn.x=(qv.x-mu)*rstd*g.x+be.x; qn.y=(qv.y-mu)*rstd*g.y+be.y;
        qn.z=(qv.z-mu)*rstd*g.z+be.z; qn.w=(qv.w-mu)*rstd*g.w+be.w;
        *reinterpret_cast<float4*>(&s_qn[t*CDIM + c]) = qn;
    }
    __syncthreads();
    {
        const int h = w & 3; const int cg = w >> 2;
        const int c0 = cg*128 + lane; const int c1 = c0 + 64;
        const float* wk0 = Wk + (size_t)c0*CDIM + h*DHEAD;
        const float* wk1 = Wk + (size_t)c1*CDIM + h*DHEAD;
        float acc0[TBF], acc1[TBF];
        #pragma unroll
        for (int t = 0; t < TBF; ++t) { acc0[t]=0.f; acc1[t]=0.f; }
        for (int d4 = 0; d4 < DHEAD/4; ++d4) {
            const float4 wa = *reinterpret_cast<const float4*>(wk0 + d4*4);
            const float4 wb = *reinterpret_cast<const float4*>(wk1 + d4*4);
            #pragma unroll
            for (int t = 0; t < TBF; ++t) {
                const float4 qv = *reinterpret_cast<const float4*>(&s_qn[t*CDIM + h*DHEAD + d4*4]);
                acc0[t] += qv.x*wa.x + qv.y*wa.y + qv.z*wa.z + qv.w*wa.w;
                acc1[t] += qv.x*wb.x + qv.y*wb.y + qv.z*wb.z + qv.w*wb.w;
            }
        }
        #pragma unroll
        for (int t = 0; t < TBF; ++t) {
            s_qk[(t*NHEADS+h)*CDIM + c0] = acc0[t];
            s_qk[(t*NHEADS+h)*CDIM + c1] = acc1[t];
        }
    }
    __syncthreads();
    {
        const int t = w; const int n = lane >> 3; const int cs = lane & 7;
        const float* cb = ctx + ((size_t)(tok0 + t)*NV + n)*CDIM;
        float p0=0,p1=0,p2=0,p3=0;
        #pragma unroll
        for (int i = 0; i < 8; ++i) {
            const int c = i*32 + cs*4;
            const float4 cv = *reinterpret_cast<const float4*>(cb + c);
            const float4 k0 = *reinterpret_cast<const float4*>(&s_qk[(t*NHEADS+0)*CDIM + c]);
            const float4 k1 = *reinterpret_cast<const float4*>(&s_qk[(t*NHEADS+1)*CDIM + c]);
            const float4 k2 = *reinterpret_cast<const float4*>(&s_qk[(t*NHEADS+2)*CDIM + c]);
            const float4 k3 = *reinterpret_cast<const float4*>(&s_qk[(t*NHEADS+3)*CDIM + c]);
            p0 += cv.x*k0.x+cv.y*k0.y+cv.z*k0.z+cv.w*k0.w;
            p1 += cv.x*k1.x+cv.y*k1.y+cv.z*k1.z+cv.w*k1.w;
            p2 += cv.x*k2.x+cv.y*k2.y+cv.z*k2.z+cv.w*k2.w;
            p3 += cv.x*k3.x+cv.y*k3.y+cv.z*k3.z+cv.w*k3.w;
        }
        #pragma unroll
        for (int off = 4; off >= 1; off >>= 1) {
            p0 += __shfl_xor(p0, off); p1 += __shfl_xor(p1, off);
            p2 += __shfl_xor(p2, off); p3 += __shfl_xor(p3, off);
        }
        if (cs == 0) {
            s_sc[(t*NV+n)*NHEADS+0] = p0*0.125f; s_sc[(t*NV+n)*NHEADS+1] = p1*0.125f;
            s_sc[(t*NV+n)*NHEADS+2] = p2*0.125f; s_sc[(t*NV+n)*NHEADS+3] = p3*0.125f;
        }
    }
    __syncthreads();
    float* s_out = s_qn;
    {
        float4 z; z.x=z.y=z.z=z.w=0.f;
        reinterpret_cast<float4*>(s_out)[tid] = z;
        if (tid < TBF*NHEADS) {
            const int t = tid >> 2; const int h = tid & 3;
            float sc[NV]; float m = -1e30f;
            #pragma unroll
            for (int n = 0; n < NV; ++n) { sc[n] = s_sc[(t*NV+n)*NHEADS+h]; m = fmaxf(m, sc[n]); }
            float sum = 0.f;
            #pragma unroll
            for (int n = 0; n < NV; ++n) { sc[n] = __expf(sc[n]-m); sum += sc[n]; }
            const float inv = 1.f/sum;
            const int tok = tok0 + t; const int b = tok >> 13; const int l = tok & (LSEQ-1);
            float* pdst = probs_out + (((size_t)b*NHEADS + h)*LSEQ + l)*NV;
            #pragma unroll
            for (int n = 0; n < NV; ++n) { const float p = sc[n]*inv; s_sc[(t*NV+n)*NHEADS+h] = p; pdst[n] = p; }
        }
    }
    __syncthreads();
    {
        const int t = w;
        const float* cbase = ctx + ((size_t)(tok0 + t)*NV)*CDIM;
        float4 a0,a1,a2,a3; a0.x=a0.y=a0.z=a0.w=0.f; a1=a0; a2=a0; a3=a0;
        for (int n = 0; n < NV; ++n) {
            const float4 pr = *reinterpret_cast<const float4*>(&s_sc[(t*NV+n)*NHEADS]);
            const float4 cv = *reinterpret_cast<const float4*>(cbase + (size_t)n*CDIM + lane*4);
            a0.x+=pr.x*cv.x; a0.y+=pr.x*cv.y; a0.z+=pr.x*cv.z; a0.w+=pr.x*cv.w;
            a1.x+=pr.y*cv.x; a1.y+=pr.y*cv.y; a1.z+=pr.y*cv.z; a1.w+=pr.y*cv.w;
            a2.x+=pr.z*cv.x; a2.y+=pr.z*cv.y; a2.z+=pr.z*cv.z; a2.w+=pr.z*cv.w;
            a3.x+=pr.w*cv.x; a3.y+=pr.w*cv.y; a3.z+=pr.w*cv.z; a3.w+=pr.w*cv.w;
        }
        *reinterpret_cast<float4*>(&s_qk[(t*NHEADS+0)*CDIM + lane*4]) = a0;
        *reinterpret_cast<float4*>(&s_qk[(t*NHEADS+1)*CDIM + lane*4]) = a1;
        *reinterpret_cast<float4*>(&s_qk[(t*NHEADS+2)*CDIM + lane*4]) = a2;
        *reinterpret_cast<float4*>(&s_qk[(t*NHEADS+3)*CDIM + lane*4]) = a3;
    }
    __syncthreads();
    {
        const int h = w & 3; const int cg = w >> 2;
        float acc[TBF];
        #pragma unroll
        for (int t = 0; t < TBF; ++t) acc[t] = 0.f;
        const float* wvbase = Wv + h*DHEAD + lane;
        for (int c4 = 0; c4 < 32; ++c4) {
            const int c = cg*128 + c4*4;
            const float wv0 = wvbase[(size_t)(c+0)*CDIM];
            const float wv1 = wvbase[(size_t)(c+1)*CDIM];
            const float wv2 = wvbase[(size_t)(c+2)*CDIM];
            const float wv3 = wvbase[(size_t)(c+3)*CDIM];
            #pragma unroll
            for (int t = 0; t < TBF; ++t) {
                const float4 wc = *reinterpret_cast<const float4*>(&s_qk[(t*NHEADS+h)*CDIM + c]);
                acc[t] += wc.x*wv0 + wc.y*wv1 + wc.z*wv2 + wc.w*wv3;
            }
        }
        #pragma unroll
        for (int t = 0; t < TBF; ++t) atomicAdd(&s_out[t*CDIM + h*DHEAD + lane], acc[t]);
    }
    __syncthreads();
    {
        const int t = w; const int c = lane * 4;
        float4 o = *reinterpret_cast<const float4*>(&s_out[t*CDIM + c]);
        const float4 bvv = *reinterpret_cast<const float4*>(bv + c);
        o.x += bvv.x; o.y += bvv.y; o.z += bvv.z; o.w += bvv.w;
        *reinterpret_cast<float4*>(out + (size_t)(tok0 + t)*CDIM + c) = o;
    }
}

extern "C" void kernel_launch(void* const* d_in, const int* in_sizes, int n_in,
                              void* d_out, int out_size, void* d_ws, size_t ws_size,
                              hipStream_t stream) {
    const float* q     = (const float*)d_in[0];
    const float* ctx   = (const float*)d_in[1];
    const float* Wk    = (const float*)d_in[2];
    // d_in[3] = bk: per-(t,h) constant across the Nv scores -> cancels in softmax; unused.
    const float* Wv    = (const float*)d_in[4];
    const float* bv    = (const float*)d_in[5];
    const float* gamma = (const float*)d_in[6];
    const float* beta  = (const float*)d_in[7];

    float* out   = (float*)d_out;
    float* probs = out + (size_t)NB * LSEQ * CDIM;

    const int n_tok = NB * LSEQ;               // 32768
    const size_t ws_need = (size_t)2 * 131072 * sizeof(u16);   // 512 KB

    if (d_ws != nullptr && ws_size >= ws_need) {
        u16* wkf = (u16*)d_ws;
        u16* wvf = wkf + 131072;
        hipLaunchKernelGGL(prep_frags, dim3(128), dim3(256), 0, stream, Wk, Wv, wkf, wvf);
        hipLaunchKernelGGL(triplane_fused, dim3(n_tok / TB), dim3(1024), 0, stream,
                           q, ctx, wkf, wvf, bv, gamma, beta, out, probs);
    } else {
        hipLaunchKernelGGL(triplane_fused_v1, dim3(n_tok / TBF), dim3(512), 0, stream,
                           q, ctx, Wk, Wv, bv, gamma, beta, out, probs);
    }
}

// Round 13
// 96.895 us; speedup vs baseline: 1.2037x; 1.0058x over previous
//
#include <hip/hip_runtime.h>
#include <math.h>

#define TB     16      // tokens per workgroup (= MFMA M, all real rows)
#define CDIM   256
#define NHEADS 4
#define DHEAD  64
#define NV     8
#define LSEQ   8192
#define NB     4

typedef short  bf16x8 __attribute__((ext_vector_type(8)));
typedef float  f32x4  __attribute__((ext_vector_type(4)));
typedef unsigned short u16;

// ---- bf16 helper (RNE) ----
static __device__ __forceinline__ u16 f2bf(float x) {
    unsigned u = __float_as_uint(x);
    unsigned r = ((u >> 16) & 1u) + 0x7fffu;
    return (u16)((u + r) >> 16);
}

// =====================================================================
// Pre-pass: convert Wk, Wv (fp32) into MFMA B-fragment-ready bf16
// layouts in workspace. Round-13: HI-ONLY (lo halves unread since r7;
// computing them doubled this serialized pre-pass for nothing).
// Layout unchanged from r3 (lo slots left uninitialized, never read):
//  wkf unit = (((h*2+kc)*16+nt)*2+s)*64 + lane ; Wk pre-scaled by 1/8.
//  wvf unit = (((h*8+kc)*4+nt)*2+s)*64 + lane ; only s=0 written.
// =====================================================================
__global__ __launch_bounds__(256) void prep_frags(
    const float* __restrict__ Wk, const float* __restrict__ Wv,
    u16* __restrict__ wkf, u16* __restrict__ wvf)
{
    const int tid = blockIdx.x * 256 + threadIdx.x;   // 0..16383
    union { u16 u[8]; uint4 v; } pk;
    if (tid < 8192) {                       // wkf hi units
        const int l = tid & 63;
        int r = tid >> 6;                   // (h*2+kc)*16+nt, 0..127
        const int nt = r & 15; r >>= 4;
        const int kc = r & 1;  r >>= 1;
        const int h  = r & 3;
        const int c     = nt * 16 + (l & 15);
        const int dbase = h * DHEAD + kc * 32 + (l >> 4) * 8;
        #pragma unroll
        for (int j = 0; j < 8; ++j)
            pk.u[j] = f2bf(Wk[(size_t)c * CDIM + dbase + j] * 0.125f);
        const size_t unit = (size_t)(tid >> 6) * 128 + l;   // s=0 slot
        *reinterpret_cast<uint4*>(wkf + unit * 8) = pk.v;
    } else {                                // wvf hi units
        const int t2 = tid - 8192;          // 0..8191
        const int l = t2 & 63;
        int r = t2 >> 6;                    // (h*8+kc)*4+nt, 0..127
        const int nt = r & 3; r >>= 2;
        const int kc = r & 7; r >>= 3;
        const int h  = r & 3;
        const int d     = h * DHEAD + nt * 16 + (l & 15);
        const int cbase = kc * 32 + (l >> 4) * 8;
        #pragma unroll
        for (int j = 0; j < 8; ++j)
            pk.u[j] = f2bf(Wv[(size_t)(cbase + j) * CDIM + d]);
        const size_t unit = (size_t)(t2 >> 6) * 128 + l;    // s=0 slot
        *reinterpret_cast<uint4*>(wvf + unit * 8) = pk.v;
    }
}

// =====================================================================
// Main fused kernel. Round-13 = round-12 (verified 97.5 us) plus
// s_setprio(1) around the two MFMA clusters (T5): the CU's 2
// independently-barriered blocks drift out of phase, so priority keeps
// the matrix pipe fed while the other block issues memory ops.
// Structure: TB=16, 1024 thr, LDS 72KB -> 2 blocks/CU (32 waves);
// hi-only weights+activations; 1/8 scale folded into wkf; 3 barriers;
// token-major qk with same-wave wctx aliasing; probs stores deferred
// past the last barrier.
// =====================================================================
__global__ __launch_bounds__(1024, 8) void triplane_fused(
    const float* __restrict__ q,
    const float* __restrict__ ctx,
    const u16*   __restrict__ wkf,
    const u16*   __restrict__ wvf,
    const float* __restrict__ bv,
    const float* __restrict__ gamma,
    const float* __restrict__ beta,
    float* __restrict__ out,
    float* __restrict__ probs_out)
{
    __shared__ __align__(16) float s_qk[TB * NHEADS * CDIM];  // 65536 B: fp32 qk (token-major,
                                                              // 4KB/token); lower 2KB/token reused
                                                              // as bf16 wctx by the SAME wave
    __shared__ __align__(16) u16   s_qnh[TB * CDIM];          // 8192 B qn hi (XOR-swizzled rows)
    // total 73728 B -> 2 blocks/CU (32 waves)

    const int tid  = threadIdx.x;
    const int w    = tid >> 6;    // wave 0..15
    const int lane = tid & 63;
    const int tok0 = blockIdx.x * TB;
    const f32x4 zero4 = {0.f, 0.f, 0.f, 0.f};

    const int h  = w & 3;         // head for phases A and D
    const int cq = w >> 2;        // c-quarter (A) / d-quarter (D), 0..3

    // ---------- Phase 0: LayerNorm(q) -> bf16 hi in swizzled LDS ----------
    {
        const int t = w;          // wave <-> token, 16 tokens
        const int c = lane * 4;
        const float4 qv = *reinterpret_cast<const float4*>(q + (size_t)(tok0 + t) * CDIM + c);
        float s  = qv.x + qv.y + qv.z + qv.w;
        float s2 = qv.x*qv.x + qv.y*qv.y + qv.z*qv.z + qv.w*qv.w;
        #pragma unroll
        for (int off = 32; off >= 1; off >>= 1) {
            s  += __shfl_xor(s,  off);
            s2 += __shfl_xor(s2, off);
        }
        const float mu   = s  * (1.0f / CDIM);
        const float var  = s2 * (1.0f / CDIM) - mu * mu;
        const float rstd = rsqrtf(var + 1e-5f);
        const float4 g  = *reinterpret_cast<const float4*>(gamma + c);
        const float4 be = *reinterpret_cast<const float4*>(beta + c);
        ushort4 vh;
        vh.x = f2bf((qv.x - mu) * rstd * g.x + be.x);
        vh.y = f2bf((qv.y - mu) * rstd * g.y + be.y);
        vh.z = f2bf((qv.z - mu) * rstd * g.z + be.z);
        vh.w = f2bf((qv.w - mu) * rstd * g.w + be.w);
        const int off = t * 512 + ((lane * 8) ^ (t << 4));   // byte offset, 8B aligned
        *reinterpret_cast<ushort4*>(reinterpret_cast<char*>(s_qnh) + off) = vh;
    }
    __syncthreads();

    // ---------- Phase A (MFMA): qk[t][h][c] = qn_h[t][:] . (Wk/8)_h^T[:][c] ----------
    // wave (h, cq): 64 c's (4 n-tiles). M=16 real tokens, K=64 (kc=0,1).
    // 1 MFMA per (nt,kc): aH * bH (qn-lo and weight-lo dropped).
    {
        const int arow = lane & 15;      // token row (real)
        const int akq  = lane >> 4;      // k quarter
        bf16x8 aH[2];
        #pragma unroll
        for (int kc = 0; kc < 2; ++kc) {
            const int intra = (h * DHEAD + kc * 32 + akq * 8) * 2;  // 16B aligned
            const int off   = arow * 512 + (intra ^ (arow << 4));
            aH[kc] = *reinterpret_cast<const bf16x8*>(reinterpret_cast<const char*>(s_qnh) + off);
        }
        __builtin_amdgcn_s_setprio(1);
        #pragma unroll
        for (int nt = 0; nt < 4; ++nt) {
            const int ntg = cq * 4 + nt;          // global n-tile 0..15
            f32x4 acc = zero4;
            #pragma unroll
            for (int kc = 0; kc < 2; ++kc) {
                const u16* p = wkf + ((size_t)(h * 4096 + kc * 2048 + ntg * 128) + lane) * 8;
                const bf16x8 bH = *reinterpret_cast<const bf16x8*>(p);
                acc = __builtin_amdgcn_mfma_f32_16x16x32_bf16(aH[kc], bH, acc, 0, 0, 0);
            }
            // C layout: col = lane&15, row = (lane>>4)*4 + reg ; all 16 rows real
            const int cc = ntg * 16 + (lane & 15);
            #pragma unroll
            for (int reg = 0; reg < 4; ++reg) {
                const int t = (lane >> 4) * 4 + reg;
                s_qk[(t * NHEADS + h) * CDIM + cc] = acc[reg];   // token-major: t*1024 + h*256 + c
            }
        }
        __builtin_amdgcn_s_setprio(0);
    }
    __syncthreads();

    // ---------- Phase B + softmax (all in registers) ----------
    // scores[t][h][n] = sum_c ctx[t][n][c]*qk[t][h][c]   (1/8 folded into Wk)
    // lane = (n = lane>>3, cs = lane&7); reduce over cs (3 shfl levels),
    // then softmax over n-groups (shfl offs 8/16/32). p0..p3 = probs(t,n,h0..3).
    float p0, p1, p2, p3;
    {
        const int t  = w;
        const int cs = lane & 7;
        const float* cb = ctx + ((size_t)(tok0 + t) * NV + (lane >> 3)) * CDIM + cs * 4;
        p0 = 0.f; p1 = 0.f; p2 = 0.f; p3 = 0.f;
        #pragma unroll
        for (int i = 0; i < 8; ++i) {
            const int c = i * 32 + cs * 4;
            const float4 cv = *reinterpret_cast<const float4*>(cb + i * 32);
            const float4 k0 = *reinterpret_cast<const float4*>(&s_qk[(t*NHEADS+0)*CDIM + c]);
            const float4 k1 = *reinterpret_cast<const float4*>(&s_qk[(t*NHEADS+1)*CDIM + c]);
            const float4 k2 = *reinterpret_cast<const float4*>(&s_qk[(t*NHEADS+2)*CDIM + c]);
            const float4 k3 = *reinterpret_cast<const float4*>(&s_qk[(t*NHEADS+3)*CDIM + c]);
            p0 += cv.x*k0.x + cv.y*k0.y + cv.z*k0.z + cv.w*k0.w;
            p1 += cv.x*k1.x + cv.y*k1.y + cv.z*k1.z + cv.w*k1.w;
            p2 += cv.x*k2.x + cv.y*k2.y + cv.z*k2.z + cv.w*k2.w;
            p3 += cv.x*k3.x + cv.y*k3.y + cv.z*k3.z + cv.w*k3.w;
        }
        #pragma unroll
        for (int off = 4; off >= 1; off >>= 1) {
            p0 += __shfl_xor(p0, off);
            p1 += __shfl_xor(p1, off);
            p2 += __shfl_xor(p2, off);
            p3 += __shfl_xor(p3, off);
        }
        // softmax over n (lane bits 3..5)
        float m0 = p0, m1 = p1, m2 = p2, m3 = p3;
        #pragma unroll
        for (int off = 8; off <= 32; off <<= 1) {
            m0 = fmaxf(m0, __shfl_xor(m0, off));
            m1 = fmaxf(m1, __shfl_xor(m1, off));
            m2 = fmaxf(m2, __shfl_xor(m2, off));
            m3 = fmaxf(m3, __shfl_xor(m3, off));
        }
        p0 = __expf(p0 - m0); p1 = __expf(p1 - m1);
        p2 = __expf(p2 - m2); p3 = __expf(p3 - m3);
        float s0 = p0, s1 = p1, s2 = p2, s3 = p3;
        #pragma unroll
        for (int off = 8; off <= 32; off <<= 1) {
            s0 += __shfl_xor(s0, off);
            s1 += __shfl_xor(s1, off);
            s2 += __shfl_xor(s2, off);
            s3 += __shfl_xor(s3, off);
        }
        p0 /= s0; p1 /= s1; p2 /= s2; p3 /= s3;
        // probs_out store DEFERRED to after phase D (keeps the C->D
        // barrier's vmcnt(0) drain free of these scattered stores).
    }
    // NO barrier: phase C below only overwrites THIS wave's token slot in
    // s_qk, which only THIS wave read in phase B (token-major layout).

    // ---------- Phase C: wctx[t][h][c] -> bf16 HI into token t's own qk slot ----------
    // write addr: t*4096 + h*512 + (lane*8 ^ ((t&7)<<4))  [bytes]
    {
        const int t = w;
        const float* cbase = ctx + ((size_t)(tok0 + t) * NV) * CDIM + lane * 4;
        float4 a0, a1, a2, a3;
        a0.x=a0.y=a0.z=a0.w=0.f; a1=a0; a2=a0; a3=a0;
        #pragma unroll
        for (int n = 0; n < NV; ++n) {
            const float prx = __shfl(p0, n * 8);
            const float pry = __shfl(p1, n * 8);
            const float prz = __shfl(p2, n * 8);
            const float prw = __shfl(p3, n * 8);
            const float4 cv = *reinterpret_cast<const float4*>(cbase + (size_t)n * CDIM);
            a0.x += prx*cv.x; a0.y += prx*cv.y; a0.z += prx*cv.z; a0.w += prx*cv.w;
            a1.x += pry*cv.x; a1.y += pry*cv.y; a1.z += pry*cv.z; a1.w += pry*cv.w;
            a2.x += prz*cv.x; a2.y += prz*cv.y; a2.z += prz*cv.z; a2.w += prz*cv.w;
            a3.x += prw*cv.x; a3.y += prw*cv.y; a3.z += prw*cv.z; a3.w += prw*cv.w;
        }
        char* base = reinterpret_cast<char*>(s_qk) + t * 4096;
        const int xo = (lane * 8) ^ ((t & 7) << 4);
        #pragma unroll
        for (int hh = 0; hh < 4; ++hh) {
            const float4 v = (hh == 0) ? a0 : (hh == 1) ? a1 : (hh == 2) ? a2 : a3;
            ushort4 vh;
            vh.x = f2bf(v.x); vh.y = f2bf(v.y); vh.z = f2bf(v.z); vh.w = f2bf(v.w);
            *reinterpret_cast<ushort4*>(base + hh * 512 + xo) = vh;
        }
    }
    __syncthreads();   // phase D reads all tokens' wctx (cross-wave)

    // ---------- Phase D (MFMA): out[t][h*64+d] = wctx_h[t][:] . Wv_h[:][d] + bv ----------
    // wave (h, dq): one 16-d n-tile. K=256 (8 kc chunks); 1 MFMA per kc.
    // wctx read token-major: arow*4096 + h*512 + ((kc*64+akq*16) ^ ((arow&7)<<4))
    {
        const int arow = lane & 15;      // token row (real)
        const int akq  = lane >> 4;
        const int nt   = cq;             // d-quarter = n-tile
        const char* wch = reinterpret_cast<const char*>(s_qk);
        const u16* wvbase = wvf + ((size_t)(h * 4096) + lane) * 8;
        f32x4 acc = zero4;
        __builtin_amdgcn_s_setprio(1);
        #pragma unroll
        for (int kc = 0; kc < 8; ++kc) {
            const int intra = kc * 64 + akq * 16;
            const int off   = arow * 4096 + h * 512 + (intra ^ ((arow & 7) << 4));
            const bf16x8 aH = *reinterpret_cast<const bf16x8*>(wch + off);
            const u16* pp = wvbase + (size_t)(kc * 512 + nt * 128) * 8;
            const bf16x8 bH = *reinterpret_cast<const bf16x8*>(pp);
            acc = __builtin_amdgcn_mfma_f32_16x16x32_bf16(aH, bH, acc, 0, 0, 0);
        }
        __builtin_amdgcn_s_setprio(0);
        const int d = h * DHEAD + nt * 16 + (lane & 15);
        const float bvv = bv[d];
        #pragma unroll
        for (int reg = 0; reg < 4; ++reg) {
            const int t = (lane >> 4) * 4 + reg;
            out[(size_t)(tok0 + t) * CDIM + d] = acc[reg] + bvv;
        }
    }

    // ---------- Deferred probs_out store (from phase B registers) ----------
    {
        const int cs = lane & 7;
        if (cs == 0) {
            const int t = w;
            const int tok = tok0 + t;
            const int b = tok >> 13;
            const int l = tok & (LSEQ - 1);
            const int n = lane >> 3;
            float* pb = probs_out + (((size_t)b * NHEADS) * LSEQ + l) * NV + n;
            pb[0 * LSEQ * NV] = p0;
            pb[1 * LSEQ * NV] = p1;
            pb[2 * LSEQ * NV] = p2;
            pb[3 * LSEQ * NV] = p3;
        }
    }
}

// =====================================================================
// Fallback (round-1 vector kernel) if workspace is too small.
// =====================================================================
static __device__ __forceinline__ float bf2f_fb(u16 h) {
    return __uint_as_float(((unsigned)h) << 16);
}
#define TBF 8
__global__ __launch_bounds__(512, 6) void triplane_fused_v1(
    const float* __restrict__ q, const float* __restrict__ ctx,
    const float* __restrict__ Wk, const float* __restrict__ Wv,
    const float* __restrict__ bv, const float* __restrict__ gamma,
    const float* __restrict__ beta, float* __restrict__ out,
    float* __restrict__ probs_out)
{
    __shared__ float s_qn[TBF * CDIM];
    __shared__ float s_qk[TBF * NHEADS * CDIM];
    __shared__ float s_sc[TBF * NV * NHEADS];
    const int tid  = threadIdx.x;
    const int w    = tid >> 6;
    const int lane = tid & 63;
    const int tok0 = blockIdx.x * TBF;
    {
        const int t = w; const int c = lane * 4;
        const float4 qv = *reinterpret_cast<const float4*>(q + (size_t)(tok0 + t) * CDIM + c);
        float s  = qv.x + qv.y + qv.z + qv.w;
        float s2 = qv.x*qv.x + qv.y*qv.y + qv.z*qv.z + qv.w*qv.w;
        #pragma unroll
        for (int off = 32; off >= 1; off >>= 1) { s += __shfl_xor(s, off); s2 += __shfl_xor(s2, off); }
        const float mu = s * (1.0f/CDIM);
        const float var = s2 * (1.0f/CDIM) - mu*mu;
        const float rstd = rsqrtf(var + 1e-5f);
        const float4 g  = *reinterpret_cast<const float4*>(gamma + c);
        const float4 be = *reinterpret_cast<const float4*>(beta + c);
        float4 qn;
        qn.x=(qv.x-mu)*rstd*g.x+be.x; qn.y=(qv.y-mu)*rstd*g.y+be.y;
        qn.z=(qv.z-mu)*rstd*g.z+be.z; qn.w=(qv.w-mu)*rstd*g.w+be.w;
        *reinterpret_cast<float4*>(&s_qn[t*CDIM + c]) = qn;
    }
    __syncthreads();
    {
        const int h = w & 3; const int cg = w >> 2;
        const int c0 = cg*128 + lane; const int c1 = c0 + 64;
        const float* wk0 = Wk + (size_t)c0*CDIM + h*DHEAD;
        const float* wk1 = Wk + (size_t)c1*CDIM + h*DHEAD;
        float acc0[TBF], acc1[TBF];
        #pragma unroll
        for (int t = 0; t < TBF; ++t) { acc0[t]=0.f; acc1[t]=0.f; }
        for (int d4 = 0; d4 < DHEAD/4; ++d4) {
            const float4 wa = *reinterpret_cast<const float4*>(wk0 + d4*4);
            const float4 wb = *reinterpret_cast<const float4*>(wk1 + d4*4);
            #pragma unroll
            for (int t = 0; t < TBF; ++t) {
                const float4 qv = *reinterpret_cast<const float4*>(&s_qn[t*CDIM + h*DHEAD + d4*4]);
                acc0[t] += qv.x*wa.x + qv.y*wa.y + qv.z*wa.z + qv.w*wa.w;
                acc1[t] += qv.x*wb.x + qv.y*wb.y + qv.z*wb.z + qv.w*wb.w;
            }
        }
        #pragma unroll
        for (int t = 0; t < TBF; ++t) {
            s_qk[(t*NHEADS+h)*CDIM + c0] = acc0[t];
            s_qk[(t*NHEADS+h)*CDIM + c1] = acc1[t];
        }
    }
    __syncthreads();
    {
        const int t = w; const int n = lane >> 3; const int cs = lane & 7;
        const float* cb = ctx + ((size_t)(tok0 + t)*NV + n)*CDIM;
        float p0=0,p1=0,p2=0,p3=0;
        #pragma unroll
        for (int i = 0; i < 8; ++i) {
            const int c = i*32 + cs*4;
            const float4 cv = *reinterpret_cast<const float4*>(cb + c);
            const float4 k0 = *reinterpret_cast<const float4*>(&s_qk[(t*NHEADS+0)*CDIM + c]);
            const float4 k1 = *reinterpret_cast<const float4*>(&s_qk[(t*NHEADS+1)*CDIM + c]);
            const float4 k2 = *reinterpret_cast<const float4*>(&s_qk[(t*NHEADS+2)*CDIM + c]);
            const float4 k3 = *reinterpret_cast<const float4*>(&s_qk[(t*NHEADS+3)*CDIM + c]);
            p0 += cv.x*k0.x+cv.y*k0.y+cv.z*k0.z+cv.w*k0.w;
            p1 += cv.x*k1.x+cv.y*k1.y+cv.z*k1.z+cv.w*k1.w;
            p2 += cv.x*k2.x+cv.y*k2.y+cv.z*k2.z+cv.w*k2.w;
            p3 += cv.x*k3.x+cv.y*k3.y+cv.z*k3.z+cv.w*k3.w;
        }
        #pragma unroll
        for (int off = 4; off >= 1; off >>= 1) {
            p0 += __shfl_xor(p0, off); p1 += __shfl_xor(p1, off);
            p2 += __shfl_xor(p2, off); p3 += __shfl_xor(p3, off);
        }
        if (cs == 0) {
            s_sc[(t*NV+n)*NHEADS+0] = p0*0.125f; s_sc[(t*NV+n)*NHEADS+1] = p1*0.125f;
            s_sc[(t*NV+n)*NHEADS+2] = p2*0.125f; s_sc[(t*NV+n)*NHEADS+3] = p3*0.125f;
        }
    }
    __syncthreads();
    float* s_out = s_qn;
    {
        float4 z; z.x=z.y=z.z=z.w=0.f;
        reinterpret_cast<float4*>(s_out)[tid] = z;
        if (tid < TBF*NHEADS) {
            const int t = tid >> 2; const int h = tid & 3;
            float sc[NV]; float m = -1e30f;
            #pragma unroll
            for (int n = 0; n < NV; ++n) { sc[n] = s_sc[(t*NV+n)*NHEADS+h]; m = fmaxf(m, sc[n]); }
            float sum = 0.f;
            #pragma unroll
            for (int n = 0; n < NV; ++n) { sc[n] = __expf(sc[n]-m); sum += sc[n]; }
            const float inv = 1.f/sum;
            const int tok = tok0 + t; const int b = tok >> 13; const int l = tok & (LSEQ-1);
            float* pdst = probs_out + (((size_t)b*NHEADS + h)*LSEQ + l)*NV;
            #pragma unroll
            for (int n = 0; n < NV; ++n) { const float p = sc[n]*inv; s_sc[(t*NV+n)*NHEADS+h] = p; pdst[n] = p; }
        }
    }
    __syncthreads();
    {
        const int t = w;
        const float* cbase = ctx + ((size_t)(tok0 + t)*NV)*CDIM;
        float4 a0,a1,a2,a3; a0.x=a0.y=a0.z=a0.w=0.f; a1=a0; a2=a0; a3=a0;
        for (int n = 0; n < NV; ++n) {
            const float4 pr = *reinterpret_cast<const float4*>(&s_sc[(t*NV+n)*NHEADS]);
            const float4 cv = *reinterpret_cast<const float4*>(cbase + (size_t)n*CDIM + lane*4);
            a0.x+=pr.x*cv.x; a0.y+=pr.x*cv.y; a0.z+=pr.x*cv.z; a0.w+=pr.x*cv.w;
            a1.x+=pr.y*cv.x; a1.y+=pr.y*cv.y; a1.z+=pr.y*cv.z; a1.w+=pr.y*cv.w;
            a2.x+=pr.z*cv.x; a2.y+=pr.z*cv.y; a2.z+=pr.z*cv.z; a2.w+=pr.z*cv.w;
            a3.x+=pr.w*cv.x; a3.y+=pr.w*cv.y; a3.z+=pr.w*cv.z; a3.w+=pr.w*cv.w;
        }
        *reinterpret_cast<float4*>(&s_qk[(t*NHEADS+0)*CDIM + lane*4]) = a0;
        *reinterpret_cast<float4*>(&s_qk[(t*NHEADS+1)*CDIM + lane*4]) = a1;
        *reinterpret_cast<float4*>(&s_qk[(t*NHEADS+2)*CDIM + lane*4]) = a2;
        *reinterpret_cast<float4*>(&s_qk[(t*NHEADS+3)*CDIM + lane*4]) = a3;
    }
    __syncthreads();
    {
        const int h = w & 3; const int cg = w >> 2;
        float acc[TBF];
        #pragma unroll
        for (int t = 0; t < TBF; ++t) acc[t] = 0.f;
        const float* wvbase = Wv + h*DHEAD + lane;
        for (int c4 = 0; c4 < 32; ++c4) {
            const int c = cg*128 + c4*4;
            const float wv0 = wvbase[(size_t)(c+0)*CDIM];
            const float wv1 = wvbase[(size_t)(c+1)*CDIM];
            const float wv2 = wvbase[(size_t)(c+2)*CDIM];
            const float wv3 = wvbase[(size_t)(c+3)*CDIM];
            #pragma unroll
            for (int t = 0; t < TBF; ++t) {
                const float4 wc = *reinterpret_cast<const float4*>(&s_qk[(t*NHEADS+h)*CDIM + c]);
                acc[t] += wc.x*wv0 + wc.y*wv1 + wc.z*wv2 + wc.w*wv3;
            }
        }
        #pragma unroll
        for (int t = 0; t < TBF; ++t) atomicAdd(&s_out[t*CDIM + h*DHEAD + lane], acc[t]);
    }
    __syncthreads();
    {
        const int t = w; const int c = lane * 4;
        float4 o = *reinterpret_cast<const float4*>(&s_out[t*CDIM + c]);
        const float4 bvv = *reinterpret_cast<const float4*>(bv + c);
        o.x += bvv.x; o.y += bvv.y; o.z += bvv.z; o.w += bvv.w;
        *reinterpret_cast<float4*>(out + (size_t)(tok0 + t)*CDIM + c) = o;
    }
}

extern "C" void kernel_launch(void* const* d_in, const int* in_sizes, int n_in,
                              void* d_out, int out_size, void* d_ws, size_t ws_size,
                              hipStream_t stream) {
    const float* q     = (const float*)d_in[0];
    const float* ctx   = (const float*)d_in[1];
    const float* Wk    = (const float*)d_in[2];
    // d_in[3] = bk: per-(t,h) constant across the Nv scores -> cancels in softmax; unused.
    const float* Wv    = (const float*)d_in[4];
    const float* bv    = (const float*)d_in[5];
    const float* gamma = (const float*)d_in[6];
    const float* beta  = (const float*)d_in[7];

    float* out   = (float*)d_out;
    float* probs = out + (size_t)NB * LSEQ * CDIM;

    const int n_tok = NB * LSEQ;               // 32768
    const size_t ws_need = (size_t)2 * 131072 * sizeof(u16);   // 512 KB

    if (d_ws != nullptr && ws_size >= ws_need) {
        u16* wkf = (u16*)d_ws;
        u16* wvf = wkf + 131072;
        hipLaunchKernelGGL(prep_frags, dim3(64), dim3(256), 0, stream, Wk, Wv, wkf, wvf);
        hipLaunchKernelGGL(triplane_fused, dim3(n_tok / TB), dim3(1024), 0, stream,
                           q, ctx, wkf, wvf, bv, gamma, beta, out, probs);
    } else {
        hipLaunchKernelGGL(triplane_fused_v1, dim3(n_tok / TBF), dim3(512), 0, stream,
                           q, ctx, Wk, Wv, bv, gamma, beta, out, probs);
    }
}

// Round 14
// 96.450 us; speedup vs baseline: 1.2093x; 1.0046x over previous
//
#include <hip/hip_runtime.h>
#include <math.h>

#define TB     16      // tokens per workgroup (= MFMA M, all real rows)
#define CDIM   256
#define NHEADS 4
#define DHEAD  64
#define NV     8
#define LSEQ   8192
#define NB     4

typedef short  bf16x8 __attribute__((ext_vector_type(8)));
typedef float  f32x4  __attribute__((ext_vector_type(4)));
typedef unsigned short u16;

// ---- bf16 helpers (RNE) ----
static __device__ __forceinline__ u16 f2bf(float x) {
    unsigned u = __float_as_uint(x);
    unsigned r = ((u >> 16) & 1u) + 0x7fffu;
    return (u16)((u + r) >> 16);
}
static __device__ __forceinline__ float bf2f(u16 h) {
    return __uint_as_float(((unsigned)h) << 16);
}
static __device__ __forceinline__ float4 ld_bf4(const u16* p) {
    const ushort4 v = *reinterpret_cast<const ushort4*>(p);
    float4 r;
    r.x = bf2f(v.x); r.y = bf2f(v.y); r.z = bf2f(v.z); r.w = bf2f(v.w);
    return r;
}

typedef __attribute__((address_space(1))) const void glds_src_t;
typedef __attribute__((address_space(3))) void glds_dst_t;

// =====================================================================
// Pre-pass (r13, hi-only): Wk, Wv -> MFMA B-fragment bf16 layouts.
//  wkf unit = (((h*2+kc)*16+nt)*2+s)*64 + lane ; Wk pre-scaled by 1/8.
//  wvf unit = (((h*8+kc)*4+nt)*2+s)*64 + lane ; only s=0 written.
// =====================================================================
__global__ __launch_bounds__(256) void prep_frags(
    const float* __restrict__ Wk, const float* __restrict__ Wv,
    u16* __restrict__ wkf, u16* __restrict__ wvf)
{
    const int tid = blockIdx.x * 256 + threadIdx.x;   // 0..16383
    union { u16 u[8]; uint4 v; } pk;
    if (tid < 8192) {                       // wkf hi units
        const int l = tid & 63;
        int r = tid >> 6;
        const int nt = r & 15; r >>= 4;
        const int kc = r & 1;  r >>= 1;
        const int h  = r & 3;
        const int c     = nt * 16 + (l & 15);
        const int dbase = h * DHEAD + kc * 32 + (l >> 4) * 8;
        #pragma unroll
        for (int j = 0; j < 8; ++j)
            pk.u[j] = f2bf(Wk[(size_t)c * CDIM + dbase + j] * 0.125f);
        const size_t unit = (size_t)(tid >> 6) * 128 + l;   // s=0 slot
        *reinterpret_cast<uint4*>(wkf + unit * 8) = pk.v;
    } else {                                // wvf hi units
        const int t2 = tid - 8192;
        const int l = t2 & 63;
        int r = t2 >> 6;
        const int nt = r & 3; r >>= 2;
        const int kc = r & 7; r >>= 3;
        const int h  = r & 3;
        const int d     = h * DHEAD + nt * 16 + (l & 15);
        const int cbase = kc * 32 + (l >> 4) * 8;
        #pragma unroll
        for (int j = 0; j < 8; ++j)
            pk.u[j] = f2bf(Wv[(size_t)(cbase + j) * CDIM + d]);
        const size_t unit = (size_t)(t2 >> 6) * 128 + l;    // s=0 slot
        *reinterpret_cast<uint4*>(wvf + unit * 8) = pk.v;
    }
}

// =====================================================================
// Main fused kernel. Round-14 changes on the r13 base (96.9 us):
//  - ASYNC ctx PREFETCH: ctx cols 0..63 (all rows, all 16 tokens; 32KB)
//    DMA'd to LDS via global_load_lds issued at phase-A start. The
//    intrinsic has LDS side effects, so the compiler cannot sink it
//    (unlike r4/r8 register prefetch); the A->B barrier's vmcnt(0)
//    drain is the completion guarantee. 25% of phase-B's serial HBM
//    burst now overlaps the whole weight-streaming phase A.
//  - qk stored bf16 (32KB, frees the LDS for the prefetch). Adds
//    ~2e-3 score err -> absmax ~0.011 vs 0.0284 threshold.
//  LDS: qk 32KB + qn 8KB + ctx 32KB = 72KB -> 2 blocks/CU (unchanged).
// =====================================================================
__global__ __launch_bounds__(1024, 8) void triplane_fused(
    const float* __restrict__ q,
    const float* __restrict__ ctx,
    const u16*   __restrict__ wkf,
    const u16*   __restrict__ wvf,
    const float* __restrict__ bv,
    const float* __restrict__ gamma,
    const float* __restrict__ beta,
    float* __restrict__ out,
    float* __restrict__ probs_out)
{
    __shared__ __align__(16) u16   s_qkh[TB * NHEADS * CDIM]; // 32768 B bf16 qk, token-major
                                                              // 2KB/token; reused as wctx by SAME wave
    __shared__ __align__(16) u16   s_qnh[TB * CDIM];          // 8192 B qn hi (XOR-swizzled rows)
    __shared__ __align__(16) float s_ctx[TB * NV * 64];       // 32768 B ctx cols 0..63 (async DMA)
    // total 73728 B -> 2 blocks/CU (32 waves)

    const int tid  = threadIdx.x;
    const int w    = tid >> 6;    // wave 0..15
    const int lane = tid & 63;
    const int tok0 = blockIdx.x * TB;
    const f32x4 zero4 = {0.f, 0.f, 0.f, 0.f};

    const int h  = w & 3;         // head for phases A and D
    const int cq = w >> 2;        // c-quarter (A) / d-quarter (D), 0..3

    // ---------- Phase 0: LayerNorm(q) -> bf16 hi in swizzled LDS ----------
    {
        const int t = w;          // wave <-> token, 16 tokens
        const int c = lane * 4;
        const float4 qv = *reinterpret_cast<const float4*>(q + (size_t)(tok0 + t) * CDIM + c);
        float s  = qv.x + qv.y + qv.z + qv.w;
        float s2 = qv.x*qv.x + qv.y*qv.y + qv.z*qv.z + qv.w*qv.w;
        #pragma unroll
        for (int off = 32; off >= 1; off >>= 1) {
            s  += __shfl_xor(s,  off);
            s2 += __shfl_xor(s2, off);
        }
        const float mu   = s  * (1.0f / CDIM);
        const float var  = s2 * (1.0f / CDIM) - mu * mu;
        const float rstd = rsqrtf(var + 1e-5f);
        const float4 g  = *reinterpret_cast<const float4*>(gamma + c);
        const float4 be = *reinterpret_cast<const float4*>(beta + c);
        ushort4 vh;
        vh.x = f2bf((qv.x - mu) * rstd * g.x + be.x);
        vh.y = f2bf((qv.y - mu) * rstd * g.y + be.y);
        vh.z = f2bf((qv.z - mu) * rstd * g.z + be.z);
        vh.w = f2bf((qv.w - mu) * rstd * g.w + be.w);
        const int off = t * 512 + ((lane * 8) ^ (t << 4));   // byte offset, 8B aligned
        *reinterpret_cast<ushort4*>(reinterpret_cast<char*>(s_qnh) + off) = vh;
    }
    __syncthreads();

    // ---------- Async ctx prefetch (issued at phase-A start) ----------
    // Wave w DMAs ctx[tok0+w][n=0..7][cols 0..63] -> s_ctx[w] (2KB linear).
    // Lane l sources row (l>>4), 16B at col (l&15)*4; two instrs cover 8 rows.
    // Completion guaranteed by the A->B barrier's vmcnt(0) drain.
    {
        const int t = w;
        const float* gsrc = ctx + ((size_t)(tok0 + t) * NV + (lane >> 4)) * CDIM + (lane & 15) * 4;
        char* ldst = reinterpret_cast<char*>(s_ctx) + t * 2048;
        __builtin_amdgcn_global_load_lds((glds_src_t*)gsrc,
                                         (glds_dst_t*)ldst, 16, 0, 0);
        __builtin_amdgcn_global_load_lds((glds_src_t*)(gsrc + 4 * CDIM),
                                         (glds_dst_t*)(ldst + 1024), 16, 0, 0);
    }

    // ---------- Phase A (MFMA): qk[t][h][c] = qn_h[t][:] . (Wk/8)_h^T[:][c] ----------
    // wave (h, cq): 64 c's (4 n-tiles). M=16 real tokens, K=64 (kc=0,1).
    {
        const int arow = lane & 15;      // token row (real)
        const int akq  = lane >> 4;      // k quarter
        bf16x8 aH[2];
        #pragma unroll
        for (int kc = 0; kc < 2; ++kc) {
            const int intra = (h * DHEAD + kc * 32 + akq * 8) * 2;  // 16B aligned
            const int off   = arow * 512 + (intra ^ (arow << 4));
            aH[kc] = *reinterpret_cast<const bf16x8*>(reinterpret_cast<const char*>(s_qnh) + off);
        }
        __builtin_amdgcn_s_setprio(1);
        #pragma unroll
        for (int nt = 0; nt < 4; ++nt) {
            const int ntg = cq * 4 + nt;          // global n-tile 0..15
            f32x4 acc = zero4;
            #pragma unroll
            for (int kc = 0; kc < 2; ++kc) {
                const u16* p = wkf + ((size_t)(h * 4096 + kc * 2048 + ntg * 128) + lane) * 8;
                const bf16x8 bH = *reinterpret_cast<const bf16x8*>(p);
                acc = __builtin_amdgcn_mfma_f32_16x16x32_bf16(aH[kc], bH, acc, 0, 0, 0);
            }
            // C layout: col = lane&15, row = (lane>>4)*4 + reg ; all 16 rows real
            const int cc = ntg * 16 + (lane & 15);
            #pragma unroll
            for (int reg = 0; reg < 4; ++reg) {
                const int t = (lane >> 4) * 4 + reg;
                s_qkh[(t * NHEADS + h) * CDIM + cc] = f2bf(acc[reg]);  // token-major bf16
            }
        }
        __builtin_amdgcn_s_setprio(0);
    }
    __syncthreads();   // also drains the ctx DMA (vmcnt(0))

    // ---------- Phase B + softmax (all in registers) ----------
    // scores[t][h][n] = sum_c ctx[t][n][c]*qk[t][h][c]   (1/8 folded into Wk)
    // lane = (n = lane>>3, cs = lane&7). ctx cols 0..63 from LDS (prefetched),
    // cols 64..255 from global. qk read as bf16 + convert.
    float p0, p1, p2, p3;
    {
        const int t  = w;
        const int n  = lane >> 3;
        const int cs = lane & 7;
        const float* cb = ctx + ((size_t)(tok0 + t) * NV + n) * CDIM + cs * 4;
        const float* sc = s_ctx + t * 512 + n * 64 + cs * 4;   // floats
        const u16* kb = s_qkh + (size_t)t * NHEADS * CDIM;
        p0 = 0.f; p1 = 0.f; p2 = 0.f; p3 = 0.f;
        #pragma unroll
        for (int i = 0; i < 8; ++i) {
            const int c = i * 32 + cs * 4;
            const float4 cv = (i < 2)
                ? *reinterpret_cast<const float4*>(sc + i * 32)
                : *reinterpret_cast<const float4*>(cb + i * 32);
            const float4 k0 = ld_bf4(kb + 0 * CDIM + c);
            const float4 k1 = ld_bf4(kb + 1 * CDIM + c);
            const float4 k2 = ld_bf4(kb + 2 * CDIM + c);
            const float4 k3 = ld_bf4(kb + 3 * CDIM + c);
            p0 += cv.x*k0.x + cv.y*k0.y + cv.z*k0.z + cv.w*k0.w;
            p1 += cv.x*k1.x + cv.y*k1.y + cv.z*k1.z + cv.w*k1.w;
            p2 += cv.x*k2.x + cv.y*k2.y + cv.z*k2.z + cv.w*k2.w;
            p3 += cv.x*k3.x + cv.y*k3.y + cv.z*k3.z + cv.w*k3.w;
        }
        #pragma unroll
        for (int off = 4; off >= 1; off >>= 1) {
            p0 += __shfl_xor(p0, off);
            p1 += __shfl_xor(p1, off);
            p2 += __shfl_xor(p2, off);
            p3 += __shfl_xor(p3, off);
        }
        // softmax over n (lane bits 3..5)
        float m0 = p0, m1 = p1, m2 = p2, m3 = p3;
        #pragma unroll
        for (int off = 8; off <= 32; off <<= 1) {
            m0 = fmaxf(m0, __shfl_xor(m0, off));
            m1 = fmaxf(m1, __shfl_xor(m1, off));
            m2 = fmaxf(m2, __shfl_xor(m2, off));
            m3 = fmaxf(m3, __shfl_xor(m3, off));
        }
        p0 = __expf(p0 - m0); p1 = __expf(p1 - m1);
        p2 = __expf(p2 - m2); p3 = __expf(p3 - m3);
        float s0 = p0, s1 = p1, s2 = p2, s3 = p3;
        #pragma unroll
        for (int off = 8; off <= 32; off <<= 1) {
            s0 += __shfl_xor(s0, off);
            s1 += __shfl_xor(s1, off);
            s2 += __shfl_xor(s2, off);
            s3 += __shfl_xor(s3, off);
        }
        p0 /= s0; p1 /= s1; p2 /= s2; p3 /= s3;
        // probs_out store DEFERRED past the last barrier (r12).
    }
    // NO barrier: phase C below only overwrites THIS wave's token slot in
    // s_qkh, which only THIS wave read in phase B (token-major layout).

    // ---------- Phase C: wctx[t][h][c] -> bf16 into token t's own qk slot ----------
    // write addr: t*2048 + h*512 + (lane*8 ^ ((t&7)<<4))  [bytes]
    {
        const int t = w;
        const float* cbase = ctx + ((size_t)(tok0 + t) * NV) * CDIM + lane * 4;
        float4 a0, a1, a2, a3;
        a0.x=a0.y=a0.z=a0.w=0.f; a1=a0; a2=a0; a3=a0;
        #pragma unroll
        for (int n = 0; n < NV; ++n) {
            const float prx = __shfl(p0, n * 8);
            const float pry = __shfl(p1, n * 8);
            const float prz = __shfl(p2, n * 8);
            const float prw = __shfl(p3, n * 8);
            const float4 cv = *reinterpret_cast<const float4*>(cbase + (size_t)n * CDIM);
            a0.x += prx*cv.x; a0.y += prx*cv.y; a0.z += prx*cv.z; a0.w += prx*cv.w;
            a1.x += pry*cv.x; a1.y += pry*cv.y; a1.z += pry*cv.z; a1.w += pry*cv.w;
            a2.x += prz*cv.x; a2.y += prz*cv.y; a2.z += prz*cv.z; a2.w += prz*cv.w;
            a3.x += prw*cv.x; a3.y += prw*cv.y; a3.z += prw*cv.z; a3.w += prw*cv.w;
        }
        char* base = reinterpret_cast<char*>(s_qkh) + t * 2048;
        const int xo = (lane * 8) ^ ((t & 7) << 4);
        #pragma unroll
        for (int hh = 0; hh < 4; ++hh) {
            const float4 v = (hh == 0) ? a0 : (hh == 1) ? a1 : (hh == 2) ? a2 : a3;
            ushort4 vh;
            vh.x = f2bf(v.x); vh.y = f2bf(v.y); vh.z = f2bf(v.z); vh.w = f2bf(v.w);
            *reinterpret_cast<ushort4*>(base + hh * 512 + xo) = vh;
        }
    }
    __syncthreads();   // phase D reads all tokens' wctx (cross-wave)

    // ---------- Phase D (MFMA): out[t][h*64+d] = wctx_h[t][:] . Wv_h[:][d] + bv ----------
    // wave (h, dq): one 16-d n-tile. K=256 (8 kc chunks); 1 MFMA per kc.
    // wctx read token-major: arow*2048 + h*512 + ((kc*64+akq*16) ^ ((arow&7)<<4))
    {
        const int arow = lane & 15;      // token row (real)
        const int akq  = lane >> 4;
        const int nt   = cq;             // d-quarter = n-tile
        const char* wch = reinterpret_cast<const char*>(s_qkh);
        const u16* wvbase = wvf + ((size_t)(h * 4096) + lane) * 8;
        f32x4 acc = zero4;
        __builtin_amdgcn_s_setprio(1);
        #pragma unroll
        for (int kc = 0; kc < 8; ++kc) {
            const int intra = kc * 64 + akq * 16;
            const int off   = arow * 2048 + h * 512 + (intra ^ ((arow & 7) << 4));
            const bf16x8 aH = *reinterpret_cast<const bf16x8*>(wch + off);
            const u16* pp = wvbase + (size_t)(kc * 512 + nt * 128) * 8;
            const bf16x8 bH = *reinterpret_cast<const bf16x8*>(pp);
            acc = __builtin_amdgcn_mfma_f32_16x16x32_bf16(aH, bH, acc, 0, 0, 0);
        }
        __builtin_amdgcn_s_setprio(0);
        const int d = h * DHEAD + nt * 16 + (lane & 15);
        const float bvv = bv[d];
        #pragma unroll
        for (int reg = 0; reg < 4; ++reg) {
            const int t = (lane >> 4) * 4 + reg;
            out[(size_t)(tok0 + t) * CDIM + d] = acc[reg] + bvv;
        }
    }

    // ---------- Deferred probs_out store (from phase B registers) ----------
    {
        const int cs = lane & 7;
        if (cs == 0) {
            const int t = w;
            const int tok = tok0 + t;
            const int b = tok >> 13;
            const int l = tok & (LSEQ - 1);
            const int n = lane >> 3;
            float* pb = probs_out + (((size_t)b * NHEADS) * LSEQ + l) * NV + n;
            pb[0 * LSEQ * NV] = p0;
            pb[1 * LSEQ * NV] = p1;
            pb[2 * LSEQ * NV] = p2;
            pb[3 * LSEQ * NV] = p3;
        }
    }
}

// =====================================================================
// Fallback (round-1 vector kernel) if workspace is too small.
// =====================================================================
#define TBF 8
__global__ __launch_bounds__(512, 6) void triplane_fused_v1(
    const float* __restrict__ q, const float* __restrict__ ctx,
    const float* __restrict__ Wk, const float* __restrict__ Wv,
    const float* __restrict__ bv, const float* __restrict__ gamma,
    const float* __restrict__ beta, float* __restrict__ out,
    float* __restrict__ probs_out)
{
    __shared__ float s_qn[TBF * CDIM];
    __shared__ float s_qk[TBF * NHEADS * CDIM];
    __shared__ float s_sc[TBF * NV * NHEADS];
    const int tid  = threadIdx.x;
    const int w    = tid >> 6;
    const int lane = tid & 63;
    const int tok0 = blockIdx.x * TBF;
    {
        const int t = w; const int c = lane * 4;
        const float4 qv = *reinterpret_cast<const float4*>(q + (size_t)(tok0 + t) * CDIM + c);
        float s  = qv.x + qv.y + qv.z + qv.w;
        float s2 = qv.x*qv.x + qv.y*qv.y + qv.z*qv.z + qv.w*qv.w;
        #pragma unroll
        for (int off = 32; off >= 1; off >>= 1) { s += __shfl_xor(s, off); s2 += __shfl_xor(s2, off); }
        const float mu = s * (1.0f/CDIM);
        const float var = s2 * (1.0f/CDIM) - mu*mu;
        const float rstd = rsqrtf(var + 1e-5f);
        const float4 g  = *reinterpret_cast<const float4*>(gamma + c);
        const float4 be = *reinterpret_cast<const float4*>(beta + c);
        float4 qn;
        qn.x=(qv.x-mu)*rstd*g.x+be.x; qn.y=(qv.y-mu)*rstd*g.y+be.y;
        qn.z=(qv.z-mu)*rstd*g.z+be.z; qn.w=(qv.w-mu)*rstd*g.w+be.w;
        *reinterpret_cast<float4*>(&s_qn[t*CDIM + c]) = qn;
    }
    __syncthreads();
    {
        const int h = w & 3; const int cg = w >> 2;
        const int c0 = cg*128 + lane; const int c1 = c0 + 64;
        const float* wk0 = Wk + (size_t)c0*CDIM + h*DHEAD;
        const float* wk1 = Wk + (size_t)c1*CDIM + h*DHEAD;
        float acc0[TBF], acc1[TBF];
        #pragma unroll
        for (int t = 0; t < TBF; ++t) { acc0[t]=0.f; acc1[t]=0.f; }
        for (int d4 = 0; d4 < DHEAD/4; ++d4) {
            const float4 wa = *reinterpret_cast<const float4*>(wk0 + d4*4);
            const float4 wb = *reinterpret_cast<const float4*>(wk1 + d4*4);
            #pragma unroll
            for (int t = 0; t < TBF; ++t) {
                const float4 qv = *reinterpret_cast<const float4*>(&s_qn[t*CDIM + h*DHEAD + d4*4]);
                acc0[t] += qv.x*wa.x + qv.y*wa.y + qv.z*wa.z + qv.w*wa.w;
                acc1[t] += qv.x*wb.x + qv.y*wb.y + qv.z*wb.z + qv.w*wb.w;
            }
        }
        #pragma unroll
        for (int t = 0; t < TBF; ++t) {
            s_qk[(t*NHEADS+h)*CDIM + c0] = acc0[t];
            s_qk[(t*NHEADS+h)*CDIM + c1] = acc1[t];
        }
    }
    __syncthreads();
    {
        const int t = w; const int n = lane >> 3; const int cs = lane & 7;
        const float* cb = ctx + ((size_t)(tok0 + t)*NV + n)*CDIM;
        float p0=0,p1=0,p2=0,p3=0;
        #pragma unroll
        for (int i = 0; i < 8; ++i) {
            const int c = i*32 + cs*4;
            const float4 cv = *reinterpret_cast<const float4*>(cb + c);
            const float4 k0 = *reinterpret_cast<const float4*>(&s_qk[(t*NHEADS+0)*CDIM + c]);
            const float4 k1 = *reinterpret_cast<const float4*>(&s_qk[(t*NHEADS+1)*CDIM + c]);
            const float4 k2 = *reinterpret_cast<const float4*>(&s_qk[(t*NHEADS+2)*CDIM + c]);
            const float4 k3 = *reinterpret_cast<const float4*>(&s_qk[(t*NHEADS+3)*CDIM + c]);
            p0 += cv.x*k0.x+cv.y*k0.y+cv.z*k0.z+cv.w*k0.w;
            p1 += cv.x*k1.x+cv.y*k1.y+cv.z*k1.z+cv.w*k1.w;
            p2 += cv.x*k2.x+cv.y*k2.y+cv.z*k2.z+cv.w*k2.w;
            p3 += cv.x*k3.x+cv.y*k3.y+cv.z*k3.z+cv.w*k3.w;
        }
        #pragma unroll
        for (int off = 4; off >= 1; off >>= 1) {
            p0 += __shfl_xor(p0, off); p1 += __shfl_xor(p1, off);
            p2 += __shfl_xor(p2, off); p3 += __shfl_xor(p3, off);
        }
        if (cs == 0) {
            s_sc[(t*NV+n)*NHEADS+0] = p0*0.125f; s_sc[(t*NV+n)*NHEADS+1] = p1*0.125f;
            s_sc[(t*NV+n)*NHEADS+2] = p2*0.125f; s_sc[(t*NV+n)*NHEADS+3] = p3*0.125f;
        }
    }
    __syncthreads();
    float* s_out = s_qn;
    {
        float4 z; z.x=z.y=z.z=z.w=0.f;
        reinterpret_cast<float4*>(s_out)[tid] = z;
        if (tid < TBF*NHEADS) {
            const int t = tid >> 2; const int h = tid & 3;
            float sc[NV]; float m = -1e30f;
            #pragma unroll
            for (int n = 0; n < NV; ++n) { sc[n] = s_sc[(t*NV+n)*NHEADS+h]; m = fmaxf(m, sc[n]); }
            float sum = 0.f;
            #pragma unroll
            for (int n = 0; n < NV; ++n) { sc[n] = __expf(sc[n]-m); sum += sc[n]; }
            const float inv = 1.f/sum;
            const int tok = tok0 + t; const int b = tok >> 13; const int l = tok & (LSEQ-1);
            float* pdst = probs_out + (((size_t)b*NHEADS + h)*LSEQ + l)*NV;
            #pragma unroll
            for (int n = 0; n < NV; ++n) { const float p = sc[n]*inv; s_sc[(t*NV+n)*NHEADS+h] = p; pdst[n] = p; }
        }
    }
    __syncthreads();
    {
        const int t = w;
        const float* cbase = ctx + ((size_t)(tok0 + t)*NV)*CDIM;
        float4 a0,a1,a2,a3; a0.x=a0.y=a0.z=a0.w=0.f; a1=a0; a2=a0; a3=a0;
        for (int n = 0; n < NV; ++n) {
            const float4 pr = *reinterpret_cast<const float4*>(&s_sc[(t*NV+n)*NHEADS]);
            const float4 cv = *reinterpret_cast<const float4*>(cbase + (size_t)n*CDIM + lane*4);
            a0.x+=pr.x*cv.x; a0.y+=pr.x*cv.y; a0.z+=pr.x*cv.z; a0.w+=pr.x*cv.w;
            a1.x+=pr.y*cv.x; a1.y+=pr.y*cv.y; a1.z+=pr.y*cv.z; a1.w+=pr.y*cv.w;
            a2.x+=pr.z*cv.x; a2.y+=pr.z*cv.y; a2.z+=pr.z*cv.z; a2.w+=pr.z*cv.w;
            a3.x+=pr.w*cv.x; a3.y+=pr.w*cv.y; a3.z+=pr.w*cv.z; a3.w+=pr.w*cv.w;
        }
        *reinterpret_cast<float4*>(&s_qk[(t*NHEADS+0)*CDIM + lane*4]) = a0;
        *reinterpret_cast<float4*>(&s_qk[(t*NHEADS+1)*CDIM + lane*4]) = a1;
        *reinterpret_cast<float4*>(&s_qk[(t*NHEADS+2)*CDIM + lane*4]) = a2;
        *reinterpret_cast<float4*>(&s_qk[(t*NHEADS+3)*CDIM + lane*4]) = a3;
    }
    __syncthreads();
    {
        const int h = w & 3; const int cg = w >> 2;
        float acc[TBF];
        #pragma unroll
        for (int t = 0; t < TBF; ++t) acc[t] = 0.f;
        const float* wvbase = Wv + h*DHEAD + lane;
        for (int c4 = 0; c4 < 32; ++c4) {
            const int c = cg*128 + c4*4;
            const float wv0 = wvbase[(size_t)(c+0)*CDIM];
            const float wv1 = wvbase[(size_t)(c+1)*CDIM];
            const float wv2 = wvbase[(size_t)(c+2)*CDIM];
            const float wv3 = wvbase[(size_t)(c+3)*CDIM];
            #pragma unroll
            for (int t = 0; t < TBF; ++t) {
                const float4 wc = *reinterpret_cast<const float4*>(&s_qk[(t*NHEADS+h)*CDIM + c]);
                acc[t] += wc.x*wv0 + wc.y*wv1 + wc.z*wv2 + wc.w*wv3;
            }
        }
        #pragma unroll
        for (int t = 0; t < TBF; ++t) atomicAdd(&s_out[t*CDIM + h*DHEAD + lane], acc[t]);
    }
    __syncthreads();
    {
        const int t = w; const int c = lane * 4;
        float4 o = *reinterpret_cast<const float4*>(&s_out[t*CDIM + c]);
        const float4 bvv = *reinterpret_cast<const float4*>(bv + c);
        o.x += bvv.x; o.y += bvv.y; o.z += bvv.z; o.w += bvv.w;
        *reinterpret_cast<float4*>(out + (size_t)(tok0 + t)*CDIM + c) = o;
    }
}

extern "C" void kernel_launch(void* const* d_in, const int* in_sizes, int n_in,
                              void* d_out, int out_size, void* d_ws, size_t ws_size,
                              hipStream_t stream) {
    const float* q     = (const float*)d_in[0];
    const float* ctx   = (const float*)d_in[1];
    const float* Wk    = (const float*)d_in[2];
    // d_in[3] = bk: per-(t,h) constant across the Nv scores -> cancels in softmax; unused.
    const float* Wv    = (const float*)d_in[4];
    const float* bv    = (const float*)d_in[5];
    const float* gamma = (const float*)d_in[6];
    const float* beta  = (const float*)d_in[7];

    float* out   = (float*)d_out;
    float* probs = out + (size_t)NB * LSEQ * CDIM;

    const int n_tok = NB * LSEQ;               // 32768
    const size_t ws_need = (size_t)2 * 131072 * sizeof(u16);   // 512 KB

    if (d_ws != nullptr && ws_size >= ws_need) {
        u16* wkf = (u16*)d_ws;
        u16* wvf = wkf + 131072;
        hipLaunchKernelGGL(prep_frags, dim3(64), dim3(256), 0, stream, Wk, Wv, wkf, wvf);
        hipLaunchKernelGGL(triplane_fused, dim3(n_tok / TB), dim3(1024), 0, stream,
                           q, ctx, wkf, wvf, bv, gamma, beta, out, probs);
    } else {
        hipLaunchKernelGGL(triplane_fused_v1, dim3(n_tok / TBF), dim3(512), 0, stream,
                           q, ctx, Wk, Wv, bv, gamma, beta, out, probs);
    }
}